// Round 2
// baseline (1310.787 us; speedup 1.0000x reference)
//
#include <hip/hip_runtime.h>

// RGCN on MI355X — round 2: adaptive-workspace, per-relation-chunked bf16 MFMA.
//   layer: t[:,rb:rb+Gr,:] = A @ W[r]  (MFMA 16x16x32 bf16, chunk of Gr relations)
//          accum[dst] += t[src, et] * norm   (fp32 atomics), chunk-filtered
//   relu fused into layer-2 GEMM A-staging (reads fp32 hpre directly).
// ws: flag | W1t | W2t | hpre(f32) | oacc(f32) | t(chunk, sized to fit ws)

#define R_NUM 16

typedef __attribute__((ext_vector_type(8))) short bf16x8;
typedef __attribute__((ext_vector_type(4))) float f32x4;

__device__ __forceinline__ float bf2f(unsigned short u) {
    unsigned int x = ((unsigned int)u) << 16;
    return __builtin_bit_cast(float, x);
}
__device__ __forceinline__ unsigned short f2bf(float f) {
    unsigned int x = __builtin_bit_cast(unsigned int, f);
    x += 0x7FFFu + ((x >> 16) & 1u);  // RNE
    return (unsigned short)(x >> 16);
}
__device__ __forceinline__ unsigned pack2(float a, float b) {
    return (unsigned)f2bf(a) | ((unsigned)f2bf(b) << 16);
}

// ---------------- dtype sniffer ----------------
// fp32 inputs: even uint16s are random mantissa halves -> ~9% in bf16-normal
// exponent band. bf16 inputs: ~100%. Threshold at 50%.
__global__ void detect_dtype(const unsigned short* __restrict__ raw, int* flag) {
    __shared__ int tot;
    if (threadIdx.x == 0) tot = 0;
    __syncthreads();
    int c = 0;
    for (int i = threadIdx.x; i < 4096; i += 256) {
        unsigned short u = raw[2 * i];
        int e = (u >> 7) & 0xFF;
        if (e >= 113 && e <= 134) c++;
    }
    atomicAdd(&tot, c);
    __syncthreads();
    if (threadIdx.x == 0) *flag = (tot > 2048) ? 1 : 0;  // 1 => bf16 inputs
}

// W[r][k][o] -> Wt[r][o][k] bf16 (one-time, small)
__global__ void transpose_w(const void* __restrict__ W, unsigned short* __restrict__ Wt,
                            int K, int O, const int* __restrict__ flagp) {
    int flag = *flagp;
    int idx = blockIdx.x * 256 + threadIdx.x;
    if (idx >= R_NUM * K * O) return;
    int k = idx % K;
    int t = idx / K;
    int o = t % O;
    int r = t / O;
    int iin = (r * K + k) * O + o;
    float v = flag ? bf2f(((const unsigned short*)W)[iin]) : ((const float*)W)[iin];
    Wt[idx] = f2bf(v);
}

// ---------------- GEMM: T[n][g][NOUT] = A[n][:128] @ W[rbase+g] ----------------
// 256 thr / 4 waves; 64-node x NOUT tile; relation = rbase + blockIdx.y.
// AMODE 0: A = feat (dtype per flag). AMODE 1: A = hpre fp32, relu fused.
// Verified MFMA 16x16x32 bf16 layouts: A[m=lane&15][k=quad*8+j],
// B[k=quad*8+j][n=lane&15], C/D col=lane&15,row=quad*4+reg.
template <int NOUT, int AMODE>
__global__ __launch_bounds__(256) void gemm_rel(const void* __restrict__ Asrc,
                                                const unsigned short* __restrict__ Wt,
                                                unsigned short* __restrict__ T, int nnodes,
                                                int rbase, const int* __restrict__ flagp) {
    constexpr int LDA = 136;
    __shared__ unsigned short lA[64 * LDA];
    __shared__ unsigned short lB[NOUT * LDA];
    const int tid = threadIdx.x;
    const int node0 = blockIdx.x * 64;
    const int rel = rbase + blockIdx.y;
    const int Gr = gridDim.y;
    const int flag = (AMODE == 0) ? *flagp : 1;

    // stage A: 64 rows x 16 segs x 8 bf16 (full 128 cols)
    for (int i = tid; i < 64 * 16; i += 256) {
        int row = i >> 4, seg = i & 15;
        int node = node0 + row;
        uint4 v = make_uint4(0u, 0u, 0u, 0u);
        if (node < nnodes) {
            if (AMODE == 1) {
                const float* p = (const float*)Asrc + (size_t)node * 128 + seg * 8;
                float4 f0 = ((const float4*)p)[0];
                float4 f1 = ((const float4*)p)[1];
                v.x = pack2(fmaxf(f0.x, 0.f), fmaxf(f0.y, 0.f));
                v.y = pack2(fmaxf(f0.z, 0.f), fmaxf(f0.w, 0.f));
                v.z = pack2(fmaxf(f1.x, 0.f), fmaxf(f1.y, 0.f));
                v.w = pack2(fmaxf(f1.z, 0.f), fmaxf(f1.w, 0.f));
            } else if (flag) {
                v = *(const uint4*)((const unsigned short*)Asrc + (size_t)node * 128 + seg * 8);
            } else {
                const float* p = (const float*)Asrc + (size_t)node * 128 + seg * 8;
                float4 f0 = ((const float4*)p)[0];
                float4 f1 = ((const float4*)p)[1];
                v.x = pack2(f0.x, f0.y);
                v.y = pack2(f0.z, f0.w);
                v.z = pack2(f1.x, f1.y);
                v.w = pack2(f1.z, f1.w);
            }
        }
        *(uint4*)(lA + row * LDA + seg * 8) = v;
    }
    // stage B: NOUT rows x 16 segs (Wt already [r][o][k])
    for (int i = tid; i < NOUT * 16; i += 256) {
        int o = i >> 4, seg = i & 15;
        *(uint4*)(lB + o * LDA + seg * 8) =
            *(const uint4*)(Wt + ((size_t)rel * NOUT + o) * 128 + seg * 8);
    }
    __syncthreads();

    const int w = tid >> 6, lane = tid & 63;
    const int quad = lane >> 4, mr = lane & 15;
    constexpr int NT = NOUT / 16;
    f32x4 acc[NT];
#pragma unroll
    for (int t = 0; t < NT; t++) acc[t] = 0.f;

    const unsigned short* pa = lA + (w * 16 + mr) * LDA + quad * 8;
    const unsigned short* pb = lB + mr * LDA + quad * 8;
#pragma unroll
    for (int kk = 0; kk < 4; kk++) {
        bf16x8 a = *(const bf16x8*)(pa + kk * 32);
#pragma unroll
        for (int nt = 0; nt < NT; nt++) {
            bf16x8 b = *(const bf16x8*)(pb + nt * 16 * LDA + kk * 32);
            acc[nt] = __builtin_amdgcn_mfma_f32_16x16x32_bf16(a, b, acc[nt], 0, 0, 0);
        }
    }

#pragma unroll
    for (int nt = 0; nt < NT; nt++) {
#pragma unroll
        for (int reg = 0; reg < 4; reg++) {
            int node = node0 + w * 16 + quad * 4 + reg;
            if (node < nnodes)
                T[((size_t)node * Gr + blockIdx.y) * NOUT + nt * 16 + mr] = f2bf(acc[nt][reg]);
        }
    }
}

// ---------------- edge scatter (chunk-filtered, grid-stride) ----------------
template <int NOUT>
__global__ void scatter_k(const unsigned short* __restrict__ T, int Gr, int rbase,
                          const void* __restrict__ nrm, const int* __restrict__ flagp,
                          const int* __restrict__ src, const int* __restrict__ dst,
                          const int* __restrict__ et, float* __restrict__ accum, int nedges) {
    constexpr int LPE = NOUT / 2;  // lanes per edge (2 bf16 per lane)
    const int flag = *flagp;
    const int epb = 256 / LPE;
    const int sub = threadIdx.x % LPE;
    const int slot = threadIdx.x / LPE;
    for (int e = blockIdx.x * epb + slot; e < nedges; e += gridDim.x * epb) {
        int g = et[e] - rbase;
        if (g < 0 || g >= Gr) continue;
        int s = src[e], d = dst[e];
        float nm = flag ? bf2f(((const unsigned short*)nrm)[e]) : ((const float*)nrm)[e];
        unsigned pv = ((const unsigned*)(T + ((size_t)s * Gr + g) * NOUT))[sub];
        float* p = accum + (size_t)d * NOUT + sub * 2;
        unsafeAtomicAdd(p, bf2f((unsigned short)(pv & 0xFFFF)) * nm);
        unsafeAtomicAdd(p + 1, bf2f((unsigned short)(pv >> 16)) * nm);
    }
}

// ---------------- final output ----------------
__global__ void write_out(const float* __restrict__ acc, void* __restrict__ dout, int n,
                          const int* __restrict__ flagp) {
    int flag = *flagp;
    int i = blockIdx.x * 256 + threadIdx.x;
    if (i >= n) return;
    float v = acc[i];
    if (flag) ((unsigned short*)dout)[i] = f2bf(v);
    else      ((float*)dout)[i] = v;
}

extern "C" void kernel_launch(void* const* d_in, const int* in_sizes, int n_in,
                              void* d_out, int out_size, void* d_ws, size_t ws_size,
                              hipStream_t stream) {
    const void* feat = d_in[0];
    const void* norm = d_in[1];
    const void* W1 = d_in[2];
    const void* W2 = d_in[3];
    const int* src = (const int*)d_in[4];
    const int* dst = (const int*)d_in[5];
    const int* et  = (const int*)d_in[6];

    const int nnodes = in_sizes[0] / 128;  // 50000
    const int nedges = in_sizes[1];        // 800000

    char* ws = (char*)d_ws;
    size_t off = 0;
    auto alloc = [&](size_t bytes) { size_t o = off; off += (bytes + 255) & ~255ULL; return o; };
    size_t off_flag = alloc(4);
    size_t off_w1t  = alloc((size_t)R_NUM * 128 * 128 * 2);
    size_t off_w2t  = alloc((size_t)R_NUM * 64 * 128 * 2);
    size_t off_hpre = alloc((size_t)nnodes * 128 * 4);
    size_t off_oacc = alloc((size_t)nnodes * 64 * 4);
    size_t t_cap = (ws_size > off) ? (ws_size - off) : 0;

    // largest power-of-2 relation-chunk widths that fit in the remaining ws
    auto pick_gr = [&](int ncol) {
        int gr = 0;
        for (int g = 16; g >= 1; g >>= 1)
            if ((size_t)nnodes * g * ncol * 2 <= t_cap) { gr = g; break; }
        return gr;
    };
    int Gr1 = pick_gr(128);
    int Gr2 = pick_gr(64);
    if (Gr1 < 1 || Gr2 < 1) {
        // distinguishable failure signature (bf16 0x4242 ~= 48.5)
        hipMemsetAsync(d_out, 0x42, (size_t)out_size * 2, stream);
        return;
    }

    int* flagp = (int*)(ws + off_flag);
    unsigned short* w1t = (unsigned short*)(ws + off_w1t);
    unsigned short* w2t = (unsigned short*)(ws + off_w2t);
    float* hpre = (float*)(ws + off_hpre);
    float* oacc = (float*)(ws + off_oacc);
    unsigned short* t = (unsigned short*)(ws + off);

    detect_dtype<<<1, 256, 0, stream>>>((const unsigned short*)feat, flagp);
    transpose_w<<<(R_NUM * 128 * 128 + 255) / 256, 256, 0, stream>>>(W1, w1t, 128, 128, flagp);
    transpose_w<<<(R_NUM * 128 * 64 + 255) / 256, 256, 0, stream>>>(W2, w2t, 128, 64, flagp);
    hipMemsetAsync(hpre, 0, (size_t)nnodes * 128 * 4, stream);
    hipMemsetAsync(oacc, 0, (size_t)nnodes * 64 * 4, stream);

    const int gx = (nnodes + 63) / 64;

    for (int rb = 0; rb < R_NUM; rb += Gr1) {
        gemm_rel<128, 0><<<dim3(gx, Gr1), 256, 0, stream>>>(feat, w1t, t, nnodes, rb, flagp);
        scatter_k<128><<<4096, 256, 0, stream>>>(t, Gr1, rb, norm, flagp, src, dst, et, hpre, nedges);
    }
    for (int rb = 0; rb < R_NUM; rb += Gr2) {
        gemm_rel<64, 1><<<dim3(gx, Gr2), 256, 0, stream>>>(hpre, w2t, t, nnodes, rb, flagp);
        scatter_k<64><<<4096, 256, 0, stream>>>(t, Gr2, rb, norm, flagp, src, dst, et, oacc, nedges);
    }

    int nout = nnodes * 64;
    write_out<<<(nout + 255) / 256, 256, 0, stream>>>(oacc, d_out, nout, flagp);
}

// Round 3
// 623.234 us; speedup vs baseline: 2.1032x; 2.1032x over previous
//
#include <hip/hip_runtime.h>

// RGCN on MI355X — round 3: atomic-free aggregation via dst-CSR.
// Fast path (ws >= ~226 MB):
//   t1 = feat @ W1[r]  (all 16 r, MFMA bf16)      -> t [N][16][128] bf16
//   CSR build: hist(dst) -> scan -> fill payload (src<<4|et, norm_f32)
//   gather1: wave per dst, fp32 reg accumulate, relu, write h bf16
//   t2 = h @ W2[r]                                 -> t [N][16][64] bf16 (reuse)
//   gather2: wave per dst, write d_out (flag dtype)
// Fallback (small ws): round-2 chunked atomic path.

#define R_NUM 16

typedef __attribute__((ext_vector_type(8))) short bf16x8;
typedef __attribute__((ext_vector_type(4))) float f32x4;

__device__ __forceinline__ float bf2f(unsigned short u) {
    unsigned int x = ((unsigned int)u) << 16;
    return __builtin_bit_cast(float, x);
}
__device__ __forceinline__ unsigned short f2bf(float f) {
    unsigned int x = __builtin_bit_cast(unsigned int, f);
    x += 0x7FFFu + ((x >> 16) & 1u);  // RNE
    return (unsigned short)(x >> 16);
}
__device__ __forceinline__ unsigned pack2(float a, float b) {
    return (unsigned)f2bf(a) | ((unsigned)f2bf(b) << 16);
}

// ---------------- dtype sniffer (fp32 vs bf16 harness inputs) ----------------
__global__ void detect_dtype(const unsigned short* __restrict__ raw, int* flag) {
    __shared__ int tot;
    if (threadIdx.x == 0) tot = 0;
    __syncthreads();
    int c = 0;
    for (int i = threadIdx.x; i < 4096; i += 256) {
        unsigned short u = raw[2 * i];
        int e = (u >> 7) & 0xFF;
        if (e >= 113 && e <= 134) c++;
    }
    atomicAdd(&tot, c);
    __syncthreads();
    if (threadIdx.x == 0) *flag = (tot > 2048) ? 1 : 0;  // 1 => bf16 inputs
}

// W[r][k][o] -> Wt[r][o][k] bf16
__global__ void transpose_w(const void* __restrict__ W, unsigned short* __restrict__ Wt,
                            int K, int O, const int* __restrict__ flagp) {
    int flag = *flagp;
    int idx = blockIdx.x * 256 + threadIdx.x;
    if (idx >= R_NUM * K * O) return;
    int k = idx % K;
    int t = idx / K;
    int o = t % O;
    int r = t / O;
    int iin = (r * K + k) * O + o;
    float v = flag ? bf2f(((const unsigned short*)W)[iin]) : ((const float*)W)[iin];
    Wt[idx] = f2bf(v);
}

// ---------------- GEMM: T[n][g][NOUT] = A[n][:128] @ W[rbase+g] ----------------
// AMODE 0: A = raw feat (dtype per flag). AMODE 1: A = fp32 + relu. AMODE 2: A = bf16.
template <int NOUT, int AMODE>
__global__ __launch_bounds__(256) void gemm_rel(const void* __restrict__ Asrc,
                                                const unsigned short* __restrict__ Wt,
                                                unsigned short* __restrict__ T, int nnodes,
                                                int rbase, const int* __restrict__ flagp) {
    constexpr int LDA = 136;
    __shared__ unsigned short lA[64 * LDA];
    __shared__ unsigned short lB[NOUT * LDA];
    const int tid = threadIdx.x;
    const int node0 = blockIdx.x * 64;
    const int rel = rbase + blockIdx.y;
    const int Gr = gridDim.y;
    const int flag = (AMODE == 0) ? *flagp : 1;

    for (int i = tid; i < 64 * 16; i += 256) {
        int row = i >> 4, seg = i & 15;
        int node = node0 + row;
        uint4 v = make_uint4(0u, 0u, 0u, 0u);
        if (node < nnodes) {
            if (AMODE == 1) {
                const float* p = (const float*)Asrc + (size_t)node * 128 + seg * 8;
                float4 f0 = ((const float4*)p)[0];
                float4 f1 = ((const float4*)p)[1];
                v.x = pack2(fmaxf(f0.x, 0.f), fmaxf(f0.y, 0.f));
                v.y = pack2(fmaxf(f0.z, 0.f), fmaxf(f0.w, 0.f));
                v.z = pack2(fmaxf(f1.x, 0.f), fmaxf(f1.y, 0.f));
                v.w = pack2(fmaxf(f1.z, 0.f), fmaxf(f1.w, 0.f));
            } else if (AMODE == 2 || flag) {
                v = *(const uint4*)((const unsigned short*)Asrc + (size_t)node * 128 + seg * 8);
            } else {
                const float* p = (const float*)Asrc + (size_t)node * 128 + seg * 8;
                float4 f0 = ((const float4*)p)[0];
                float4 f1 = ((const float4*)p)[1];
                v.x = pack2(f0.x, f0.y);
                v.y = pack2(f0.z, f0.w);
                v.z = pack2(f1.x, f1.y);
                v.w = pack2(f1.z, f1.w);
            }
        }
        *(uint4*)(lA + row * LDA + seg * 8) = v;
    }
    for (int i = tid; i < NOUT * 16; i += 256) {
        int o = i >> 4, seg = i & 15;
        *(uint4*)(lB + o * LDA + seg * 8) =
            *(const uint4*)(Wt + ((size_t)rel * NOUT + o) * 128 + seg * 8);
    }
    __syncthreads();

    const int w = tid >> 6, lane = tid & 63;
    const int quad = lane >> 4, mr = lane & 15;
    constexpr int NT = NOUT / 16;
    f32x4 acc[NT];
#pragma unroll
    for (int t = 0; t < NT; t++) acc[t] = 0.f;

    const unsigned short* pa = lA + (w * 16 + mr) * LDA + quad * 8;
    const unsigned short* pb = lB + mr * LDA + quad * 8;
#pragma unroll
    for (int kk = 0; kk < 4; kk++) {
        bf16x8 a = *(const bf16x8*)(pa + kk * 32);
#pragma unroll
        for (int nt = 0; nt < NT; nt++) {
            bf16x8 b = *(const bf16x8*)(pb + nt * 16 * LDA + kk * 32);
            acc[nt] = __builtin_amdgcn_mfma_f32_16x16x32_bf16(a, b, acc[nt], 0, 0, 0);
        }
    }

#pragma unroll
    for (int nt = 0; nt < NT; nt++) {
#pragma unroll
        for (int reg = 0; reg < 4; reg++) {
            int node = node0 + w * 16 + quad * 4 + reg;
            if (node < nnodes)
                T[((size_t)node * Gr + blockIdx.y) * NOUT + nt * 16 + mr] = f2bf(acc[nt][reg]);
        }
    }
}

// ---------------- CSR build ----------------
__global__ void hist_dst(const int* __restrict__ dst, int* __restrict__ counts, int nedges) {
    int e = blockIdx.x * 256 + threadIdx.x;
    if (e < nedges) atomicAdd(&counts[dst[e]], 1);
}

__global__ __launch_bounds__(1024) void scan_offsets(const int* __restrict__ counts,
                                                     int* __restrict__ offsets,
                                                     int* __restrict__ cursor, int n) {
    __shared__ int partials[1024];
    int t = threadIdx.x;
    int chunk = (n + 1023) / 1024;
    int lo = t * chunk;
    int hi = min(n, lo + chunk);
    int s = 0;
    for (int i = lo; i < hi; i++) s += counts[i];
    partials[t] = s;
    __syncthreads();
    for (int d = 1; d < 1024; d <<= 1) {
        int v = (t >= d) ? partials[t - d] : 0;
        __syncthreads();
        partials[t] += v;
        __syncthreads();
    }
    int run = (t == 0) ? 0 : partials[t - 1];
    for (int i = lo; i < hi; i++) {
        offsets[i] = run;
        cursor[i] = run;
        run += counts[i];
    }
    if (t == 0) offsets[n] = partials[1023];
}

__global__ void fill_payload(const int* __restrict__ src, const int* __restrict__ dst,
                             const int* __restrict__ et, const void* __restrict__ nrm,
                             const int* __restrict__ flagp, int* __restrict__ cursor,
                             uint2* __restrict__ payload, int nedges) {
    int e = blockIdx.x * 256 + threadIdx.x;
    if (e >= nedges) return;
    int flag = *flagp;
    float nm = flag ? bf2f(((const unsigned short*)nrm)[e]) : ((const float*)nrm)[e];
    int pos = atomicAdd(&cursor[dst[e]], 1);
    uint2 pl;
    pl.x = ((unsigned)src[e] << 4) | (unsigned)(et[e] & 15);
    pl.y = __builtin_bit_cast(unsigned, nm);
    payload[pos] = pl;
}

// ---------------- dst-centric gather (atomic-free) ----------------
// One wave per dst node. Batch-load 64 payloads, shfl-broadcast each edge,
// coalesced row read from T, fp32 register accumulate.
// OUTMODE 0: relu + bf16 -> h.  OUTMODE 1: d_out (flag dtype).
template <int NOUT, int OUTMODE>
__global__ __launch_bounds__(256) void gather_seg(const unsigned short* __restrict__ T,
                                                  const int* __restrict__ offsets,
                                                  const uint2* __restrict__ payload,
                                                  void* __restrict__ out, int nnodes,
                                                  const int* __restrict__ flagp) {
    constexpr int LPR = NOUT / 2;  // lanes holding data (2 vals per lane)
    const int wid = threadIdx.x >> 6;
    const int lane = threadIdx.x & 63;
    const int dst = blockIdx.x * 4 + wid;
    if (dst >= nnodes) return;
    const int beg = offsets[dst], end = offsets[dst + 1];
    float ax = 0.f, ay = 0.f;
    for (int i = beg; i < end; i += 64) {
        int cnt = min(64, end - i);
        uint2 pl = make_uint2(0u, 0u);
        if (lane < cnt) pl = payload[i + lane];
        for (int j = 0; j < cnt; j++) {
            unsigned key = (unsigned)__shfl((int)pl.x, j);
            float nm = __shfl(__builtin_bit_cast(float, pl.y), j);
            const unsigned short* row = T + ((size_t)(key >> 4) * R_NUM + (key & 15)) * NOUT;
            if (lane < LPR) {
                unsigned pv = ((const unsigned*)row)[lane];
                ax = fmaf(bf2f((unsigned short)(pv & 0xFFFF)), nm, ax);
                ay = fmaf(bf2f((unsigned short)(pv >> 16)), nm, ay);
            }
        }
    }
    if (OUTMODE == 0) {
        if (lane < LPR)
            ((unsigned*)out)[(size_t)dst * LPR + lane] = pack2(fmaxf(ax, 0.f), fmaxf(ay, 0.f));
    } else {
        int flag = *flagp;
        if (lane < LPR) {
            if (flag) {
                ((unsigned*)out)[(size_t)dst * LPR + lane] = pack2(ax, ay);
            } else {
                float2 v;
                v.x = ax; v.y = ay;
                ((float2*)out)[(size_t)dst * LPR + lane] = v;
            }
        }
    }
}

// ---------------- fallback (round-2 atomic path) ----------------
template <int NOUT>
__global__ void scatter_k(const unsigned short* __restrict__ T, int Gr, int rbase,
                          const void* __restrict__ nrm, const int* __restrict__ flagp,
                          const int* __restrict__ src, const int* __restrict__ dst,
                          const int* __restrict__ et, float* __restrict__ accum, int nedges) {
    constexpr int LPE = NOUT / 2;
    const int flag = *flagp;
    const int epb = 256 / LPE;
    const int sub = threadIdx.x % LPE;
    const int slot = threadIdx.x / LPE;
    for (int e = blockIdx.x * epb + slot; e < nedges; e += gridDim.x * epb) {
        int g = et[e] - rbase;
        if (g < 0 || g >= Gr) continue;
        int s = src[e], d = dst[e];
        float nm = flag ? bf2f(((const unsigned short*)nrm)[e]) : ((const float*)nrm)[e];
        unsigned pv = ((const unsigned*)(T + ((size_t)s * Gr + g) * NOUT))[sub];
        float* p = accum + (size_t)d * NOUT + sub * 2;
        unsafeAtomicAdd(p, bf2f((unsigned short)(pv & 0xFFFF)) * nm);
        unsafeAtomicAdd(p + 1, bf2f((unsigned short)(pv >> 16)) * nm);
    }
}

__global__ void write_out(const float* __restrict__ acc, void* __restrict__ dout, int n,
                          const int* __restrict__ flagp) {
    int flag = *flagp;
    int i = blockIdx.x * 256 + threadIdx.x;
    if (i >= n) return;
    float v = acc[i];
    if (flag) ((unsigned short*)dout)[i] = f2bf(v);
    else      ((float*)dout)[i] = v;
}

extern "C" void kernel_launch(void* const* d_in, const int* in_sizes, int n_in,
                              void* d_out, int out_size, void* d_ws, size_t ws_size,
                              hipStream_t stream) {
    const void* feat = d_in[0];
    const void* norm = d_in[1];
    const void* W1 = d_in[2];
    const void* W2 = d_in[3];
    const int* src = (const int*)d_in[4];
    const int* dst = (const int*)d_in[5];
    const int* et  = (const int*)d_in[6];

    const int nnodes = in_sizes[0] / 128;
    const int nedges = in_sizes[1];

    char* ws = (char*)d_ws;
    size_t off = 0;
    auto alloc = [&](size_t bytes) { size_t o = off; off += (bytes + 255) & ~255ULL; return o; };
    size_t off_flag = alloc(4);
    size_t off_w1t  = alloc((size_t)R_NUM * 128 * 128 * 2);
    size_t off_w2t  = alloc((size_t)R_NUM * 64 * 128 * 2);

    int* flagp = (int*)(ws + off_flag);
    unsigned short* w1t = (unsigned short*)(ws + off_w1t);
    unsigned short* w2t = (unsigned short*)(ws + off_w2t);

    // ---- fast path layout ----
    size_t f_off = off;
    auto falloc = [&](size_t bytes) { size_t o = f_off; f_off += (bytes + 255) & ~255ULL; return o; };
    size_t off_offs = falloc((size_t)(nnodes + 1) * 4);
    size_t off_curs = falloc((size_t)nnodes * 4);
    size_t off_pay  = falloc((size_t)nedges * 8);
    size_t off_hbf  = falloc((size_t)nnodes * 128 * 2);
    size_t off_t    = falloc((size_t)nnodes * R_NUM * 128 * 2);
    bool fast = (f_off <= ws_size);

    const int gx = (nnodes + 63) / 64;

    detect_dtype<<<1, 256, 0, stream>>>((const unsigned short*)feat, flagp);
    transpose_w<<<(R_NUM * 128 * 128 + 255) / 256, 256, 0, stream>>>(W1, w1t, 128, 128, flagp);
    transpose_w<<<(R_NUM * 128 * 64 + 255) / 256, 256, 0, stream>>>(W2, w2t, 128, 64, flagp);

    if (fast) {
        int* offs = (int*)(ws + off_offs);
        int* curs = (int*)(ws + off_curs);
        uint2* pay = (uint2*)(ws + off_pay);
        unsigned short* hbf = (unsigned short*)(ws + off_hbf);
        unsigned short* t = (unsigned short*)(ws + off_t);

        // CSR build (counts accumulated straight into offs slots, then scanned)
        hipMemsetAsync(offs, 0, (size_t)(nnodes + 1) * 4, stream);
        hist_dst<<<(nedges + 255) / 256, 256, 0, stream>>>(dst, offs, nedges);
        // scan reads counts from offs into curs/offs: need counts separate -> use curs as counts?
        // offs currently holds counts[0..n-1]; scan must read counts while writing offsets.
        // scan_offsets reads counts[] and writes offsets[]/cursor[]; pass offs as counts is
        // unsafe (in-place). Use curs as the histogram buffer instead:
        // (re-issue correctly below)
        // -- no-op: histogram above targeted offs; redo into curs --
        hipMemsetAsync(curs, 0, (size_t)nnodes * 4, stream);
        hist_dst<<<(nedges + 255) / 256, 256, 0, stream>>>(dst, curs, nedges);
        scan_offsets<<<1, 1024, 0, stream>>>(curs, offs, curs, nnodes);
        fill_payload<<<(nedges + 255) / 256, 256, 0, stream>>>(src, dst, et, norm, flagp,
                                                               curs, pay, nedges);

        gemm_rel<128, 0><<<dim3(gx, R_NUM), 256, 0, stream>>>(feat, w1t, t, nnodes, 0, flagp);
        gather_seg<128, 0><<<(nnodes + 3) / 4, 256, 0, stream>>>(t, offs, pay, hbf, nnodes, flagp);
        gemm_rel<64, 2><<<dim3(gx, R_NUM), 256, 0, stream>>>(hbf, w2t, t, nnodes, 0, flagp);
        gather_seg<64, 1><<<(nnodes + 3) / 4, 256, 0, stream>>>(t, offs, pay, d_out, nnodes, flagp);
        return;
    }

    // ---- fallback: round-2 chunked atomic path ----
    size_t off_hpre = alloc((size_t)nnodes * 128 * 4);
    size_t off_oacc = alloc((size_t)nnodes * 64 * 4);
    size_t t_cap = (ws_size > off) ? (ws_size - off) : 0;
    auto pick_gr = [&](int ncol) {
        int gr = 0;
        for (int g = 16; g >= 1; g >>= 1)
            if ((size_t)nnodes * g * ncol * 2 <= t_cap) { gr = g; break; }
        return gr;
    };
    int Gr1 = pick_gr(128);
    int Gr2 = pick_gr(64);
    if (Gr1 < 1 || Gr2 < 1) {
        hipMemsetAsync(d_out, 0x42, (size_t)out_size * 2, stream);
        return;
    }
    float* hpre = (float*)(ws + off_hpre);
    float* oacc = (float*)(ws + off_oacc);
    unsigned short* t = (unsigned short*)(ws + off);

    hipMemsetAsync(hpre, 0, (size_t)nnodes * 128 * 4, stream);
    hipMemsetAsync(oacc, 0, (size_t)nnodes * 64 * 4, stream);
    for (int rb = 0; rb < R_NUM; rb += Gr1) {
        gemm_rel<128, 0><<<dim3(gx, Gr1), 256, 0, stream>>>(feat, w1t, t, nnodes, rb, flagp);
        scatter_k<128><<<4096, 256, 0, stream>>>(t, Gr1, rb, norm, flagp, src, dst, et, hpre, nedges);
    }
    for (int rb = 0; rb < R_NUM; rb += Gr2) {
        gemm_rel<64, 1><<<dim3(gx, Gr2), 256, 0, stream>>>(hpre, w2t, t, nnodes, rb, flagp);
        scatter_k<64><<<4096, 256, 0, stream>>>(t, Gr2, rb, norm, flagp, src, dst, et, oacc, nedges);
    }
    int nout = nnodes * 64;
    write_out<<<(nout + 255) / 256, 256, 0, stream>>>(oacc, d_out, nout, flagp);
}

// Round 4
// 505.102 us; speedup vs baseline: 2.5951x; 1.2339x over previous
//
#include <hip/hip_runtime.h>

// RGCN on MI355X — round 4.
// Fast path:
//   t1 = feat @ W1[all 16 r]  (one block = 64-node tile, rel-loop, A-frags in regs)
//   CSR(dst) -> gather1 (wave/dst, 4x unrolled)  -> h = relu(.) bf16
//   t2 = h @ W2[all r]        (same kernel, NOUT=64)
//   gather2 (half-wave/dst)   -> d_out
// Fallback (small ws): round-2 chunked atomic path.

#define R_NUM 16

typedef __attribute__((ext_vector_type(8))) short bf16x8;
typedef __attribute__((ext_vector_type(4))) float f32x4;

__device__ __forceinline__ float bf2f(unsigned short u) {
    unsigned int x = ((unsigned int)u) << 16;
    return __builtin_bit_cast(float, x);
}
__device__ __forceinline__ unsigned short f2bf(float f) {
    unsigned int x = __builtin_bit_cast(unsigned int, f);
    x += 0x7FFFu + ((x >> 16) & 1u);  // RNE
    return (unsigned short)(x >> 16);
}
__device__ __forceinline__ unsigned pack2(float a, float b) {
    return (unsigned)f2bf(a) | ((unsigned)f2bf(b) << 16);
}
__device__ __forceinline__ float lo16(unsigned v) { return bf2f((unsigned short)(v & 0xFFFF)); }
__device__ __forceinline__ float hi16(unsigned v) { return bf2f((unsigned short)(v >> 16)); }

// ---------------- dtype sniffer (fp32 vs bf16 harness inputs) ----------------
__global__ void detect_dtype(const unsigned short* __restrict__ raw, int* flag) {
    __shared__ int tot;
    if (threadIdx.x == 0) tot = 0;
    __syncthreads();
    int c = 0;
    for (int i = threadIdx.x; i < 4096; i += 256) {
        unsigned short u = raw[2 * i];
        int e = (u >> 7) & 0xFF;
        if (e >= 113 && e <= 134) c++;
    }
    atomicAdd(&tot, c);
    __syncthreads();
    if (threadIdx.x == 0) *flag = (tot > 2048) ? 1 : 0;  // 1 => bf16 inputs
}

// Both weight transposes in one launch: W[r][k][o] -> Wt[r][o][k] bf16.
__global__ void transpose_both(const void* __restrict__ W1, const void* __restrict__ W2,
                               unsigned short* __restrict__ w1t, unsigned short* __restrict__ w2t,
                               const int* __restrict__ flagp) {
    const int flag = *flagp;
    const int n1 = R_NUM * 128 * 128;
    const int n2 = R_NUM * 128 * 64;
    int idx = blockIdx.x * 256 + threadIdx.x;
    if (idx < n1) {
        int k = idx % 128, o = (idx / 128) % 128, r = idx / (128 * 128);
        int iin = (r * 128 + k) * 128 + o;
        float v = flag ? bf2f(((const unsigned short*)W1)[iin]) : ((const float*)W1)[iin];
        w1t[idx] = f2bf(v);
    } else if (idx < n1 + n2) {
        int j = idx - n1;
        int k = j % 128, o = (j / 128) % 64, r = j / (128 * 64);
        int iin = (r * 128 + k) * 64 + o;
        float v = flag ? bf2f(((const unsigned short*)W2)[iin]) : ((const float*)W2)[iin];
        w2t[j] = f2bf(v);
    }
}

// ---------------- GEMM over all relations ----------------
// Block: 256 thr, 64-node tile. A staged to LDS once, A-frags hoisted to regs,
// loop rel=0..15 staging B per rel. Wave tile = 64M x 16N per column-tile
// (NTC = NOUT/64 column tiles), so each B-frag is read once per wave.
// AMODE 0: A = feat (dtype per flag). AMODE 2: A = bf16.
template <int NOUT, int AMODE>
__global__ __launch_bounds__(256, 3) void gemm_all(const void* __restrict__ Asrc,
                                                   const unsigned short* __restrict__ Wt,
                                                   unsigned short* __restrict__ T, int nnodes,
                                                   const int* __restrict__ flagp) {
    constexpr int LDA = 136;
    constexpr int NTC = NOUT / 64;  // column tiles per wave
    __shared__ unsigned short lA[64 * LDA];
    __shared__ unsigned short lB[NOUT * LDA];
    const int tid = threadIdx.x;
    const int node0 = blockIdx.x * 64;
    const int flag = (AMODE == 0) ? *flagp : 1;

    // stage A once: 64 rows x 16 segs x 8 bf16
    for (int i = tid; i < 64 * 16; i += 256) {
        int row = i >> 4, seg = i & 15;
        int node = node0 + row;
        uint4 v = make_uint4(0u, 0u, 0u, 0u);
        if (node < nnodes) {
            if (AMODE == 2 || flag) {
                v = *(const uint4*)((const unsigned short*)Asrc + (size_t)node * 128 + seg * 8);
            } else {
                const float* p = (const float*)Asrc + (size_t)node * 128 + seg * 8;
                float4 f0 = ((const float4*)p)[0];
                float4 f1 = ((const float4*)p)[1];
                v.x = pack2(f0.x, f0.y);
                v.y = pack2(f0.z, f0.w);
                v.z = pack2(f1.x, f1.y);
                v.w = pack2(f1.z, f1.w);
            }
        }
        *(uint4*)(lA + row * LDA + seg * 8) = v;
    }

    auto stageB = [&](int rel) {
        for (int i = tid; i < NOUT * 16; i += 256) {
            int o = i >> 4, seg = i & 15;
            *(uint4*)(lB + o * LDA + seg * 8) =
                *(const uint4*)(Wt + ((size_t)rel * NOUT + o) * 128 + seg * 8);
        }
    };
    stageB(0);
    __syncthreads();

    const int w = tid >> 6, lane = tid & 63;
    const int quad = lane >> 4, mr = lane & 15;

    // hoist all 16 A-fragments (whole 64-row tile) into registers
    bf16x8 afr[16];
#pragma unroll
    for (int mt = 0; mt < 4; mt++)
#pragma unroll
        for (int kk = 0; kk < 4; kk++)
            afr[mt * 4 + kk] = *(const bf16x8*)(lA + (mt * 16 + mr) * LDA + kk * 32 + quad * 8);

    for (int rel = 0; rel < R_NUM; rel++) {
        f32x4 acc[4][NTC];
#pragma unroll
        for (int mt = 0; mt < 4; mt++)
#pragma unroll
            for (int c = 0; c < NTC; c++) acc[mt][c] = 0.f;

#pragma unroll
        for (int kk = 0; kk < 4; kk++) {
#pragma unroll
            for (int c = 0; c < NTC; c++) {
                bf16x8 b = *(const bf16x8*)(lB + (c * 64 + w * 16 + mr) * LDA + kk * 32 + quad * 8);
#pragma unroll
                for (int mt = 0; mt < 4; mt++)
                    acc[mt][c] = __builtin_amdgcn_mfma_f32_16x16x32_bf16(afr[mt * 4 + kk], b,
                                                                         acc[mt][c], 0, 0, 0);
            }
        }
        __syncthreads();  // all waves done reading lB
        if (rel + 1 < R_NUM) stageB(rel + 1);

#pragma unroll
        for (int mt = 0; mt < 4; mt++)
#pragma unroll
            for (int c = 0; c < NTC; c++)
#pragma unroll
                for (int reg = 0; reg < 4; reg++) {
                    int node = node0 + mt * 16 + quad * 4 + reg;
                    if (node < nnodes)
                        T[((size_t)node * R_NUM + rel) * NOUT + c * 64 + w * 16 + mr] =
                            f2bf(acc[mt][c][reg]);
                }
        if (rel + 1 < R_NUM) __syncthreads();
    }
}

// ---------------- CSR build ----------------
__global__ void hist_dst(const int* __restrict__ dst, int* __restrict__ counts, int nedges) {
    int e = blockIdx.x * 256 + threadIdx.x;
    if (e < nedges) atomicAdd(&counts[dst[e]], 1);
}

__global__ __launch_bounds__(1024) void scan_offsets(const int* __restrict__ counts,
                                                     int* __restrict__ offsets,
                                                     int* __restrict__ cursor, int n) {
    __shared__ int partials[1024];
    int t = threadIdx.x;
    int chunk = (n + 1023) / 1024;
    int lo = t * chunk;
    int hi = min(n, lo + chunk);
    int s = 0;
    for (int i = lo; i < hi; i++) s += counts[i];
    partials[t] = s;
    __syncthreads();
    for (int d = 1; d < 1024; d <<= 1) {
        int v = (t >= d) ? partials[t - d] : 0;
        __syncthreads();
        partials[t] += v;
        __syncthreads();
    }
    int run = (t == 0) ? 0 : partials[t - 1];
    for (int i = lo; i < hi; i++) {
        offsets[i] = run;
        cursor[i] = run;
        run += counts[i];
    }
    if (t == 0) offsets[n] = partials[1023];
}

__global__ void fill_payload(const int* __restrict__ src, const int* __restrict__ dst,
                             const int* __restrict__ et, const void* __restrict__ nrm,
                             const int* __restrict__ flagp, int* __restrict__ cursor,
                             uint2* __restrict__ payload, int nedges) {
    int e = blockIdx.x * 256 + threadIdx.x;
    if (e >= nedges) return;
    int flag = *flagp;
    float nm = flag ? bf2f(((const unsigned short*)nrm)[e]) : ((const float*)nrm)[e];
    int pos = atomicAdd(&cursor[dst[e]], 1);
    uint2 pl;
    pl.x = ((unsigned)src[e] << 4) | (unsigned)(et[e] & 15);
    pl.y = __builtin_bit_cast(unsigned, nm);
    payload[pos] = pl;
}

// ---------------- dst-centric gather (atomic-free) ----------------
// SUBW = NOUT/2 lanes per dst (2 bf16 cols per lane). 4-wide unrolled row
// loads for memory-level parallelism. OUTMODE 0: relu+bf16. OUTMODE 1: d_out.
template <int NOUT, int OUTMODE>
__global__ __launch_bounds__(256) void gather_seg(const unsigned short* __restrict__ T,
                                                  const int* __restrict__ offsets,
                                                  const uint2* __restrict__ payload,
                                                  void* __restrict__ out, int nnodes,
                                                  const int* __restrict__ flagp) {
    constexpr int SUBW = NOUT / 2;
    const int lane = threadIdx.x & 63;
    const int ll = lane & (SUBW - 1);
    const int dpb = 256 / SUBW;
    const int dst = blockIdx.x * dpb + threadIdx.x / SUBW;
    if (dst >= nnodes) return;
    const int base = lane & ~(SUBW - 1);  // shfl base of this sub-wave
    const int beg = offsets[dst], end = offsets[dst + 1];
    float ax = 0.f, ay = 0.f;

    for (int i = beg; i < end; i += SUBW) {
        int cnt = min(SUBW, end - i);
        uint2 pl = make_uint2(0u, 0u);
        if (ll < cnt) pl = payload[i + ll];
        int j = 0;
        for (; j + 4 <= cnt; j += 4) {
            unsigned k0 = (unsigned)__shfl((int)pl.x, base + j);
            unsigned k1 = (unsigned)__shfl((int)pl.x, base + j + 1);
            unsigned k2 = (unsigned)__shfl((int)pl.x, base + j + 2);
            unsigned k3 = (unsigned)__shfl((int)pl.x, base + j + 3);
            float n0 = __builtin_bit_cast(float, (unsigned)__shfl((int)pl.y, base + j));
            float n1 = __builtin_bit_cast(float, (unsigned)__shfl((int)pl.y, base + j + 1));
            float n2 = __builtin_bit_cast(float, (unsigned)__shfl((int)pl.y, base + j + 2));
            float n3 = __builtin_bit_cast(float, (unsigned)__shfl((int)pl.y, base + j + 3));
            unsigned v0 = ((const unsigned*)(T + ((size_t)(k0 >> 4) * R_NUM + (k0 & 15)) * NOUT))[ll];
            unsigned v1 = ((const unsigned*)(T + ((size_t)(k1 >> 4) * R_NUM + (k1 & 15)) * NOUT))[ll];
            unsigned v2 = ((const unsigned*)(T + ((size_t)(k2 >> 4) * R_NUM + (k2 & 15)) * NOUT))[ll];
            unsigned v3 = ((const unsigned*)(T + ((size_t)(k3 >> 4) * R_NUM + (k3 & 15)) * NOUT))[ll];
            ax = fmaf(lo16(v0), n0, ax); ay = fmaf(hi16(v0), n0, ay);
            ax = fmaf(lo16(v1), n1, ax); ay = fmaf(hi16(v1), n1, ay);
            ax = fmaf(lo16(v2), n2, ax); ay = fmaf(hi16(v2), n2, ay);
            ax = fmaf(lo16(v3), n3, ax); ay = fmaf(hi16(v3), n3, ay);
        }
        for (; j < cnt; j++) {
            unsigned k = (unsigned)__shfl((int)pl.x, base + j);
            float nm = __builtin_bit_cast(float, (unsigned)__shfl((int)pl.y, base + j));
            unsigned v = ((const unsigned*)(T + ((size_t)(k >> 4) * R_NUM + (k & 15)) * NOUT))[ll];
            ax = fmaf(lo16(v), nm, ax);
            ay = fmaf(hi16(v), nm, ay);
        }
    }
    if (OUTMODE == 0) {
        ((unsigned*)out)[(size_t)dst * SUBW + ll] = pack2(fmaxf(ax, 0.f), fmaxf(ay, 0.f));
    } else {
        if (*flagp) {
            ((unsigned*)out)[(size_t)dst * SUBW + ll] = pack2(ax, ay);
        } else {
            float2 v;
            v.x = ax; v.y = ay;
            ((float2*)out)[(size_t)dst * SUBW + ll] = v;
        }
    }
}

// ---------------- fallback path (round-2 style, chunked + atomics) ----------------
template <int NOUT, int AMODE>
__global__ __launch_bounds__(256) void gemm_rel(const void* __restrict__ Asrc,
                                                const unsigned short* __restrict__ Wt,
                                                unsigned short* __restrict__ T, int nnodes,
                                                int rbase, const int* __restrict__ flagp) {
    constexpr int LDA = 136;
    __shared__ unsigned short lA[64 * LDA];
    __shared__ unsigned short lB[NOUT * LDA];
    const int tid = threadIdx.x;
    const int node0 = blockIdx.x * 64;
    const int rel = rbase + blockIdx.y;
    const int Gr = gridDim.y;
    const int flag = (AMODE == 0) ? *flagp : 1;

    for (int i = tid; i < 64 * 16; i += 256) {
        int row = i >> 4, seg = i & 15;
        int node = node0 + row;
        uint4 v = make_uint4(0u, 0u, 0u, 0u);
        if (node < nnodes) {
            if (AMODE == 1) {
                const float* p = (const float*)Asrc + (size_t)node * 128 + seg * 8;
                float4 f0 = ((const float4*)p)[0];
                float4 f1 = ((const float4*)p)[1];
                v.x = pack2(fmaxf(f0.x, 0.f), fmaxf(f0.y, 0.f));
                v.y = pack2(fmaxf(f0.z, 0.f), fmaxf(f0.w, 0.f));
                v.z = pack2(fmaxf(f1.x, 0.f), fmaxf(f1.y, 0.f));
                v.w = pack2(fmaxf(f1.z, 0.f), fmaxf(f1.w, 0.f));
            } else if (flag) {
                v = *(const uint4*)((const unsigned short*)Asrc + (size_t)node * 128 + seg * 8);
            } else {
                const float* p = (const float*)Asrc + (size_t)node * 128 + seg * 8;
                float4 f0 = ((const float4*)p)[0];
                float4 f1 = ((const float4*)p)[1];
                v.x = pack2(f0.x, f0.y);
                v.y = pack2(f0.z, f0.w);
                v.z = pack2(f1.x, f1.y);
                v.w = pack2(f1.z, f1.w);
            }
        }
        *(uint4*)(lA + row * LDA + seg * 8) = v;
    }
    for (int i = tid; i < NOUT * 16; i += 256) {
        int o = i >> 4, seg = i & 15;
        *(uint4*)(lB + o * LDA + seg * 8) =
            *(const uint4*)(Wt + ((size_t)rel * NOUT + o) * 128 + seg * 8);
    }
    __syncthreads();

    const int w = tid >> 6, lane = tid & 63;
    const int quad = lane >> 4, mr = lane & 15;
    constexpr int NT = NOUT / 16;
    f32x4 acc[NT];
#pragma unroll
    for (int t = 0; t < NT; t++) acc[t] = 0.f;
    const unsigned short* pa = lA + (w * 16 + mr) * LDA + quad * 8;
    const unsigned short* pb = lB + mr * LDA + quad * 8;
#pragma unroll
    for (int kk = 0; kk < 4; kk++) {
        bf16x8 a = *(const bf16x8*)(pa + kk * 32);
#pragma unroll
        for (int nt = 0; nt < NT; nt++) {
            bf16x8 b = *(const bf16x8*)(pb + nt * 16 * LDA + kk * 32);
            acc[nt] = __builtin_amdgcn_mfma_f32_16x16x32_bf16(a, b, acc[nt], 0, 0, 0);
        }
    }
#pragma unroll
    for (int nt = 0; nt < NT; nt++)
#pragma unroll
        for (int reg = 0; reg < 4; reg++) {
            int node = node0 + w * 16 + quad * 4 + reg;
            if (node < nnodes)
                T[((size_t)node * Gr + blockIdx.y) * NOUT + nt * 16 + mr] = f2bf(acc[nt][reg]);
        }
}

template <int NOUT>
__global__ void scatter_k(const unsigned short* __restrict__ T, int Gr, int rbase,
                          const void* __restrict__ nrm, const int* __restrict__ flagp,
                          const int* __restrict__ src, const int* __restrict__ dst,
                          const int* __restrict__ et, float* __restrict__ accum, int nedges) {
    constexpr int LPE = NOUT / 2;
    const int flag = *flagp;
    const int epb = 256 / LPE;
    const int sub = threadIdx.x % LPE;
    const int slot = threadIdx.x / LPE;
    for (int e = blockIdx.x * epb + slot; e < nedges; e += gridDim.x * epb) {
        int g = et[e] - rbase;
        if (g < 0 || g >= Gr) continue;
        int s = src[e], d = dst[e];
        float nm = flag ? bf2f(((const unsigned short*)nrm)[e]) : ((const float*)nrm)[e];
        unsigned pv = ((const unsigned*)(T + ((size_t)s * Gr + g) * NOUT))[sub];
        float* p = accum + (size_t)d * NOUT + sub * 2;
        unsafeAtomicAdd(p, lo16(pv) * nm);
        unsafeAtomicAdd(p + 1, hi16(pv) * nm);
    }
}

__global__ void write_out(const float* __restrict__ acc, void* __restrict__ dout, int n,
                          const int* __restrict__ flagp) {
    int flag = *flagp;
    int i = blockIdx.x * 256 + threadIdx.x;
    if (i >= n) return;
    float v = acc[i];
    if (flag) ((unsigned short*)dout)[i] = f2bf(v);
    else      ((float*)dout)[i] = v;
}

extern "C" void kernel_launch(void* const* d_in, const int* in_sizes, int n_in,
                              void* d_out, int out_size, void* d_ws, size_t ws_size,
                              hipStream_t stream) {
    const void* feat = d_in[0];
    const void* norm = d_in[1];
    const void* W1 = d_in[2];
    const void* W2 = d_in[3];
    const int* src = (const int*)d_in[4];
    const int* dst = (const int*)d_in[5];
    const int* et  = (const int*)d_in[6];

    const int nnodes = in_sizes[0] / 128;
    const int nedges = in_sizes[1];

    char* ws = (char*)d_ws;
    size_t off = 0;
    auto alloc = [&](size_t bytes) { size_t o = off; off += (bytes + 255) & ~255ULL; return o; };
    size_t off_flag = alloc(4);
    size_t off_w1t  = alloc((size_t)R_NUM * 128 * 128 * 2);
    size_t off_w2t  = alloc((size_t)R_NUM * 64 * 128 * 2);

    int* flagp = (int*)(ws + off_flag);
    unsigned short* w1t = (unsigned short*)(ws + off_w1t);
    unsigned short* w2t = (unsigned short*)(ws + off_w2t);

    // fast-path layout
    size_t f_off = off;
    auto falloc = [&](size_t bytes) { size_t o = f_off; f_off += (bytes + 255) & ~255ULL; return o; };
    size_t off_offs = falloc((size_t)(nnodes + 1) * 4);
    size_t off_curs = falloc((size_t)nnodes * 4);
    size_t off_cnt  = falloc((size_t)nnodes * 4);
    size_t off_pay  = falloc((size_t)nedges * 8);
    size_t off_hbf  = falloc((size_t)nnodes * 128 * 2);
    size_t off_t    = falloc((size_t)nnodes * R_NUM * 128 * 2);
    bool fast = (f_off <= ws_size);

    const int gx = (nnodes + 63) / 64;
    const int ntr = R_NUM * 128 * 128 + R_NUM * 128 * 64;

    detect_dtype<<<1, 256, 0, stream>>>((const unsigned short*)feat, flagp);
    transpose_both<<<(ntr + 255) / 256, 256, 0, stream>>>(W1, W2, w1t, w2t, flagp);

    if (fast) {
        int* offs = (int*)(ws + off_offs);
        int* curs = (int*)(ws + off_curs);
        int* cnt  = (int*)(ws + off_cnt);
        uint2* pay = (uint2*)(ws + off_pay);
        unsigned short* hbf = (unsigned short*)(ws + off_hbf);
        unsigned short* t = (unsigned short*)(ws + off_t);

        hipMemsetAsync(cnt, 0, (size_t)nnodes * 4, stream);
        hist_dst<<<(nedges + 255) / 256, 256, 0, stream>>>(dst, cnt, nedges);
        scan_offsets<<<1, 1024, 0, stream>>>(cnt, offs, curs, nnodes);
        fill_payload<<<(nedges + 255) / 256, 256, 0, stream>>>(src, dst, et, norm, flagp,
                                                               curs, pay, nedges);

        gemm_all<128, 0><<<gx, 256, 0, stream>>>(feat, w1t, t, nnodes, flagp);
        gather_seg<128, 0><<<(nnodes + 3) / 4, 256, 0, stream>>>(t, offs, pay, hbf, nnodes, flagp);
        gemm_all<64, 2><<<gx, 256, 0, stream>>>(hbf, w2t, t, nnodes, flagp);
        gather_seg<64, 1><<<(nnodes + 7) / 8, 256, 0, stream>>>(t, offs, pay, d_out, nnodes, flagp);
        return;
    }

    // fallback: chunked atomic path
    size_t off_hpre = alloc((size_t)nnodes * 128 * 4);
    size_t off_oacc = alloc((size_t)nnodes * 64 * 4);
    size_t t_cap = (ws_size > off) ? (ws_size - off) : 0;
    auto pick_gr = [&](int ncol) {
        int gr = 0;
        for (int g = 16; g >= 1; g >>= 1)
            if ((size_t)nnodes * g * ncol * 2 <= t_cap) { gr = g; break; }
        return gr;
    };
    int Gr1 = pick_gr(128);
    int Gr2 = pick_gr(64);
    if (Gr1 < 1 || Gr2 < 1) {
        hipMemsetAsync(d_out, 0x42, (size_t)out_size * 2, stream);
        return;
    }
    float* hpre = (float*)(ws + off_hpre);
    float* oacc = (float*)(ws + off_oacc);
    unsigned short* t = (unsigned short*)(ws + off);

    hipMemsetAsync(hpre, 0, (size_t)nnodes * 128 * 4, stream);
    hipMemsetAsync(oacc, 0, (size_t)nnodes * 64 * 4, stream);
    for (int rb = 0; rb < R_NUM; rb += Gr1) {
        gemm_rel<128, 0><<<dim3(gx, Gr1), 256, 0, stream>>>(feat, w1t, t, nnodes, rb, flagp);
        scatter_k<128><<<4096, 256, 0, stream>>>(t, Gr1, rb, norm, flagp, src, dst, et, hpre, nedges);
    }
    for (int rb = 0; rb < R_NUM; rb += Gr2) {
        gemm_rel<64, 1><<<dim3(gx, Gr2), 256, 0, stream>>>(hpre, w2t, t, nnodes, rb, flagp);
        scatter_k<64><<<4096, 256, 0, stream>>>(t, Gr2, rb, norm, flagp, src, dst, et, oacc, nedges);
    }
    int nout = nnodes * 64;
    write_out<<<(nout + 255) / 256, 256, 0, stream>>>(oacc, d_out, nout, flagp);
}

// Round 5
// 408.679 us; speedup vs baseline: 3.2074x; 1.2359x over previous
//
#include <hip/hip_runtime.h>

// RGCN on MI355X — round 5: parallel CSR scan (round-4 scan was 109 µs single-block).
// Fast path:
//   t1 = feat @ W1[all 16 r]  (block = 64-node tile, rel-loop, A-frags in regs)
//   CSR(dst): hist -> 3-phase parallel scan -> fill payload
//   gather1 (wave/dst)  -> h = relu(.) bf16
//   t2 = h @ W2[all r]  -> gather2 (half-wave/dst) -> d_out
// Fallback (small ws): chunked atomic path.

#define R_NUM 16

typedef __attribute__((ext_vector_type(8))) short bf16x8;
typedef __attribute__((ext_vector_type(4))) float f32x4;

__device__ __forceinline__ float bf2f(unsigned short u) {
    unsigned int x = ((unsigned int)u) << 16;
    return __builtin_bit_cast(float, x);
}
__device__ __forceinline__ unsigned short f2bf(float f) {
    unsigned int x = __builtin_bit_cast(unsigned int, f);
    x += 0x7FFFu + ((x >> 16) & 1u);  // RNE
    return (unsigned short)(x >> 16);
}
__device__ __forceinline__ unsigned pack2(float a, float b) {
    return (unsigned)f2bf(a) | ((unsigned)f2bf(b) << 16);
}
__device__ __forceinline__ float lo16(unsigned v) { return bf2f((unsigned short)(v & 0xFFFF)); }
__device__ __forceinline__ float hi16(unsigned v) { return bf2f((unsigned short)(v >> 16)); }

// ---------------- dtype sniffer (fp32 vs bf16 harness inputs) ----------------
__global__ void detect_dtype(const unsigned short* __restrict__ raw, int* flag) {
    __shared__ int tot;
    if (threadIdx.x == 0) tot = 0;
    __syncthreads();
    int c = 0;
    for (int i = threadIdx.x; i < 4096; i += 256) {
        unsigned short u = raw[2 * i];
        int e = (u >> 7) & 0xFF;
        if (e >= 113 && e <= 134) c++;
    }
    atomicAdd(&tot, c);
    __syncthreads();
    if (threadIdx.x == 0) *flag = (tot > 2048) ? 1 : 0;  // 1 => bf16 inputs
}

// Both weight transposes in one launch: W[r][k][o] -> Wt[r][o][k] bf16.
__global__ void transpose_both(const void* __restrict__ W1, const void* __restrict__ W2,
                               unsigned short* __restrict__ w1t, unsigned short* __restrict__ w2t,
                               const int* __restrict__ flagp) {
    const int flag = *flagp;
    const int n1 = R_NUM * 128 * 128;
    const int n2 = R_NUM * 128 * 64;
    int idx = blockIdx.x * 256 + threadIdx.x;
    if (idx < n1) {
        int k = idx % 128, o = (idx / 128) % 128, r = idx / (128 * 128);
        int iin = (r * 128 + k) * 128 + o;
        float v = flag ? bf2f(((const unsigned short*)W1)[iin]) : ((const float*)W1)[iin];
        w1t[idx] = f2bf(v);
    } else if (idx < n1 + n2) {
        int j = idx - n1;
        int k = j % 128, o = (j / 128) % 64, r = j / (128 * 64);
        int iin = (r * 128 + k) * 64 + o;
        float v = flag ? bf2f(((const unsigned short*)W2)[iin]) : ((const float*)W2)[iin];
        w2t[j] = f2bf(v);
    }
}

// ---------------- GEMM over all relations ----------------
template <int NOUT, int AMODE>
__global__ __launch_bounds__(256, 3) void gemm_all(const void* __restrict__ Asrc,
                                                   const unsigned short* __restrict__ Wt,
                                                   unsigned short* __restrict__ T, int nnodes,
                                                   const int* __restrict__ flagp) {
    constexpr int LDA = 136;
    constexpr int NTC = NOUT / 64;
    __shared__ unsigned short lA[64 * LDA];
    __shared__ unsigned short lB[NOUT * LDA];
    const int tid = threadIdx.x;
    const int node0 = blockIdx.x * 64;
    const int flag = (AMODE == 0) ? *flagp : 1;

    for (int i = tid; i < 64 * 16; i += 256) {
        int row = i >> 4, seg = i & 15;
        int node = node0 + row;
        uint4 v = make_uint4(0u, 0u, 0u, 0u);
        if (node < nnodes) {
            if (AMODE == 2 || flag) {
                v = *(const uint4*)((const unsigned short*)Asrc + (size_t)node * 128 + seg * 8);
            } else {
                const float* p = (const float*)Asrc + (size_t)node * 128 + seg * 8;
                float4 f0 = ((const float4*)p)[0];
                float4 f1 = ((const float4*)p)[1];
                v.x = pack2(f0.x, f0.y);
                v.y = pack2(f0.z, f0.w);
                v.z = pack2(f1.x, f1.y);
                v.w = pack2(f1.z, f1.w);
            }
        }
        *(uint4*)(lA + row * LDA + seg * 8) = v;
    }

    auto stageB = [&](int rel) {
        for (int i = tid; i < NOUT * 16; i += 256) {
            int o = i >> 4, seg = i & 15;
            *(uint4*)(lB + o * LDA + seg * 8) =
                *(const uint4*)(Wt + ((size_t)rel * NOUT + o) * 128 + seg * 8);
        }
    };
    stageB(0);
    __syncthreads();

    const int w = tid >> 6, lane = tid & 63;
    const int quad = lane >> 4, mr = lane & 15;

    bf16x8 afr[16];
#pragma unroll
    for (int mt = 0; mt < 4; mt++)
#pragma unroll
        for (int kk = 0; kk < 4; kk++)
            afr[mt * 4 + kk] = *(const bf16x8*)(lA + (mt * 16 + mr) * LDA + kk * 32 + quad * 8);

    for (int rel = 0; rel < R_NUM; rel++) {
        f32x4 acc[4][NTC];
#pragma unroll
        for (int mt = 0; mt < 4; mt++)
#pragma unroll
            for (int c = 0; c < NTC; c++) acc[mt][c] = 0.f;

#pragma unroll
        for (int kk = 0; kk < 4; kk++) {
#pragma unroll
            for (int c = 0; c < NTC; c++) {
                bf16x8 b = *(const bf16x8*)(lB + (c * 64 + w * 16 + mr) * LDA + kk * 32 + quad * 8);
#pragma unroll
                for (int mt = 0; mt < 4; mt++)
                    acc[mt][c] = __builtin_amdgcn_mfma_f32_16x16x32_bf16(afr[mt * 4 + kk], b,
                                                                         acc[mt][c], 0, 0, 0);
            }
        }
        __syncthreads();
        if (rel + 1 < R_NUM) stageB(rel + 1);

#pragma unroll
        for (int mt = 0; mt < 4; mt++)
#pragma unroll
            for (int c = 0; c < NTC; c++)
#pragma unroll
                for (int reg = 0; reg < 4; reg++) {
                    int node = node0 + mt * 16 + quad * 4 + reg;
                    if (node < nnodes)
                        T[((size_t)node * R_NUM + rel) * NOUT + c * 64 + w * 16 + mr] =
                            f2bf(acc[mt][c][reg]);
                }
        if (rel + 1 < R_NUM) __syncthreads();
    }
}

// ---------------- CSR build ----------------
__global__ void hist_dst(const int* __restrict__ dst, int* __restrict__ counts, int nedges) {
    int e = blockIdx.x * 256 + threadIdx.x;
    if (e < nedges) atomicAdd(&counts[dst[e]], 1);
}

// 3-phase parallel exclusive scan; 1024 counts per block, 4 per thread.
__global__ __launch_bounds__(256) void scan_phase1(const int* __restrict__ counts,
                                                   int* __restrict__ blocksums, int n) {
    __shared__ int red[256];
    int base = blockIdx.x * 1024 + threadIdx.x * 4;
    int s = 0;
#pragma unroll
    for (int j = 0; j < 4; j++) {
        int idx = base + j;
        if (idx < n) s += counts[idx];
    }
    red[threadIdx.x] = s;
    __syncthreads();
    for (int d = 128; d > 0; d >>= 1) {
        if (threadIdx.x < d) red[threadIdx.x] += red[threadIdx.x + d];
        __syncthreads();
    }
    if (threadIdx.x == 0) blocksums[blockIdx.x] = red[0];
}

__global__ __launch_bounds__(1024) void scan_phase2(const int* __restrict__ blocksums,
                                                    int* __restrict__ blockoff, int nb) {
    __shared__ int arr[1024];
    int t = threadIdx.x;
    arr[t] = (t < nb) ? blocksums[t] : 0;
    __syncthreads();
    for (int d = 1; d < 1024; d <<= 1) {
        int v = (t >= d) ? arr[t - d] : 0;
        __syncthreads();
        arr[t] += v;
        __syncthreads();
    }
    if (t < nb) blockoff[t] = (t == 0) ? 0 : arr[t - 1];
}

__global__ __launch_bounds__(256) void scan_phase3(const int* __restrict__ counts,
                                                   const int* __restrict__ blockoff,
                                                   int* __restrict__ offsets,
                                                   int* __restrict__ cursor, int n) {
    __shared__ int tsum[256];
    int base = blockIdx.x * 1024 + threadIdx.x * 4;
    int c[4];
    int s = 0;
#pragma unroll
    for (int j = 0; j < 4; j++) {
        int idx = base + j;
        c[j] = (idx < n) ? counts[idx] : 0;
        s += c[j];
    }
    tsum[threadIdx.x] = s;
    __syncthreads();
    for (int d = 1; d < 256; d <<= 1) {
        int v = (threadIdx.x >= d) ? tsum[threadIdx.x - d] : 0;
        __syncthreads();
        tsum[threadIdx.x] += v;
        __syncthreads();
    }
    int run = blockoff[blockIdx.x] + ((threadIdx.x == 0) ? 0 : tsum[threadIdx.x - 1]);
#pragma unroll
    for (int j = 0; j < 4; j++) {
        int idx = base + j;
        if (idx < n) {
            offsets[idx] = run;
            cursor[idx] = run;
            if (idx == n - 1) offsets[n] = run + c[j];
            run += c[j];
        }
    }
}

__global__ void fill_payload(const int* __restrict__ src, const int* __restrict__ dst,
                             const int* __restrict__ et, const void* __restrict__ nrm,
                             const int* __restrict__ flagp, int* __restrict__ cursor,
                             uint2* __restrict__ payload, int nedges) {
    int e = blockIdx.x * 256 + threadIdx.x;
    if (e >= nedges) return;
    int flag = *flagp;
    float nm = flag ? bf2f(((const unsigned short*)nrm)[e]) : ((const float*)nrm)[e];
    int pos = atomicAdd(&cursor[dst[e]], 1);
    uint2 pl;
    pl.x = ((unsigned)src[e] << 4) | (unsigned)(et[e] & 15);
    pl.y = __builtin_bit_cast(unsigned, nm);
    payload[pos] = pl;
}

// ---------------- dst-centric gather (atomic-free) ----------------
template <int NOUT, int OUTMODE>
__global__ __launch_bounds__(256) void gather_seg(const unsigned short* __restrict__ T,
                                                  const int* __restrict__ offsets,
                                                  const uint2* __restrict__ payload,
                                                  void* __restrict__ out, int nnodes,
                                                  const int* __restrict__ flagp) {
    constexpr int SUBW = NOUT / 2;
    const int lane = threadIdx.x & 63;
    const int ll = lane & (SUBW - 1);
    const int dpb = 256 / SUBW;
    const int dst = blockIdx.x * dpb + threadIdx.x / SUBW;
    if (dst >= nnodes) return;
    const int base = lane & ~(SUBW - 1);
    const int beg = offsets[dst], end = offsets[dst + 1];
    float ax = 0.f, ay = 0.f;

    for (int i = beg; i < end; i += SUBW) {
        int cnt = min(SUBW, end - i);
        uint2 pl = make_uint2(0u, 0u);
        if (ll < cnt) pl = payload[i + ll];
        int j = 0;
        for (; j + 4 <= cnt; j += 4) {
            unsigned k0 = (unsigned)__shfl((int)pl.x, base + j);
            unsigned k1 = (unsigned)__shfl((int)pl.x, base + j + 1);
            unsigned k2 = (unsigned)__shfl((int)pl.x, base + j + 2);
            unsigned k3 = (unsigned)__shfl((int)pl.x, base + j + 3);
            float n0 = __builtin_bit_cast(float, (unsigned)__shfl((int)pl.y, base + j));
            float n1 = __builtin_bit_cast(float, (unsigned)__shfl((int)pl.y, base + j + 1));
            float n2 = __builtin_bit_cast(float, (unsigned)__shfl((int)pl.y, base + j + 2));
            float n3 = __builtin_bit_cast(float, (unsigned)__shfl((int)pl.y, base + j + 3));
            unsigned v0 = ((const unsigned*)(T + ((size_t)(k0 >> 4) * R_NUM + (k0 & 15)) * NOUT))[ll];
            unsigned v1 = ((const unsigned*)(T + ((size_t)(k1 >> 4) * R_NUM + (k1 & 15)) * NOUT))[ll];
            unsigned v2 = ((const unsigned*)(T + ((size_t)(k2 >> 4) * R_NUM + (k2 & 15)) * NOUT))[ll];
            unsigned v3 = ((const unsigned*)(T + ((size_t)(k3 >> 4) * R_NUM + (k3 & 15)) * NOUT))[ll];
            ax = fmaf(lo16(v0), n0, ax); ay = fmaf(hi16(v0), n0, ay);
            ax = fmaf(lo16(v1), n1, ax); ay = fmaf(hi16(v1), n1, ay);
            ax = fmaf(lo16(v2), n2, ax); ay = fmaf(hi16(v2), n2, ay);
            ax = fmaf(lo16(v3), n3, ax); ay = fmaf(hi16(v3), n3, ay);
        }
        for (; j < cnt; j++) {
            unsigned k = (unsigned)__shfl((int)pl.x, base + j);
            float nm = __builtin_bit_cast(float, (unsigned)__shfl((int)pl.y, base + j));
            unsigned v = ((const unsigned*)(T + ((size_t)(k >> 4) * R_NUM + (k & 15)) * NOUT))[ll];
            ax = fmaf(lo16(v), nm, ax);
            ay = fmaf(hi16(v), nm, ay);
        }
    }
    if (OUTMODE == 0) {
        ((unsigned*)out)[(size_t)dst * SUBW + ll] = pack2(fmaxf(ax, 0.f), fmaxf(ay, 0.f));
    } else {
        if (*flagp) {
            ((unsigned*)out)[(size_t)dst * SUBW + ll] = pack2(ax, ay);
        } else {
            float2 v;
            v.x = ax; v.y = ay;
            ((float2*)out)[(size_t)dst * SUBW + ll] = v;
        }
    }
}

// ---------------- fallback path (chunked + atomics) ----------------
template <int NOUT, int AMODE>
__global__ __launch_bounds__(256) void gemm_rel(const void* __restrict__ Asrc,
                                                const unsigned short* __restrict__ Wt,
                                                unsigned short* __restrict__ T, int nnodes,
                                                int rbase, const int* __restrict__ flagp) {
    constexpr int LDA = 136;
    __shared__ unsigned short lA[64 * LDA];
    __shared__ unsigned short lB[NOUT * LDA];
    const int tid = threadIdx.x;
    const int node0 = blockIdx.x * 64;
    const int rel = rbase + blockIdx.y;
    const int Gr = gridDim.y;
    const int flag = (AMODE == 0) ? *flagp : 1;

    for (int i = tid; i < 64 * 16; i += 256) {
        int row = i >> 4, seg = i & 15;
        int node = node0 + row;
        uint4 v = make_uint4(0u, 0u, 0u, 0u);
        if (node < nnodes) {
            if (AMODE == 1) {
                const float* p = (const float*)Asrc + (size_t)node * 128 + seg * 8;
                float4 f0 = ((const float4*)p)[0];
                float4 f1 = ((const float4*)p)[1];
                v.x = pack2(fmaxf(f0.x, 0.f), fmaxf(f0.y, 0.f));
                v.y = pack2(fmaxf(f0.z, 0.f), fmaxf(f0.w, 0.f));
                v.z = pack2(fmaxf(f1.x, 0.f), fmaxf(f1.y, 0.f));
                v.w = pack2(fmaxf(f1.z, 0.f), fmaxf(f1.w, 0.f));
            } else if (flag) {
                v = *(const uint4*)((const unsigned short*)Asrc + (size_t)node * 128 + seg * 8);
            } else {
                const float* p = (const float*)Asrc + (size_t)node * 128 + seg * 8;
                float4 f0 = ((const float4*)p)[0];
                float4 f1 = ((const float4*)p)[1];
                v.x = pack2(f0.x, f0.y);
                v.y = pack2(f0.z, f0.w);
                v.z = pack2(f1.x, f1.y);
                v.w = pack2(f1.z, f1.w);
            }
        }
        *(uint4*)(lA + row * LDA + seg * 8) = v;
    }
    for (int i = tid; i < NOUT * 16; i += 256) {
        int o = i >> 4, seg = i & 15;
        *(uint4*)(lB + o * LDA + seg * 8) =
            *(const uint4*)(Wt + ((size_t)rel * NOUT + o) * 128 + seg * 8);
    }
    __syncthreads();

    const int w = tid >> 6, lane = tid & 63;
    const int quad = lane >> 4, mr = lane & 15;
    constexpr int NT = NOUT / 16;
    f32x4 acc[NT];
#pragma unroll
    for (int t = 0; t < NT; t++) acc[t] = 0.f;
    const unsigned short* pa = lA + (w * 16 + mr) * LDA + quad * 8;
    const unsigned short* pb = lB + mr * LDA + quad * 8;
#pragma unroll
    for (int kk = 0; kk < 4; kk++) {
        bf16x8 a = *(const bf16x8*)(pa + kk * 32);
#pragma unroll
        for (int nt = 0; nt < NT; nt++) {
            bf16x8 b = *(const bf16x8*)(pb + nt * 16 * LDA + kk * 32);
            acc[nt] = __builtin_amdgcn_mfma_f32_16x16x32_bf16(a, b, acc[nt], 0, 0, 0);
        }
    }
#pragma unroll
    for (int nt = 0; nt < NT; nt++)
#pragma unroll
        for (int reg = 0; reg < 4; reg++) {
            int node = node0 + w * 16 + quad * 4 + reg;
            if (node < nnodes)
                T[((size_t)node * Gr + blockIdx.y) * NOUT + nt * 16 + mr] = f2bf(acc[nt][reg]);
        }
}

template <int NOUT>
__global__ void scatter_k(const unsigned short* __restrict__ T, int Gr, int rbase,
                          const void* __restrict__ nrm, const int* __restrict__ flagp,
                          const int* __restrict__ src, const int* __restrict__ dst,
                          const int* __restrict__ et, float* __restrict__ accum, int nedges) {
    constexpr int LPE = NOUT / 2;
    const int flag = *flagp;
    const int epb = 256 / LPE;
    const int sub = threadIdx.x % LPE;
    const int slot = threadIdx.x / LPE;
    for (int e = blockIdx.x * epb + slot; e < nedges; e += gridDim.x * epb) {
        int g = et[e] - rbase;
        if (g < 0 || g >= Gr) continue;
        int s = src[e], d = dst[e];
        float nm = flag ? bf2f(((const unsigned short*)nrm)[e]) : ((const float*)nrm)[e];
        unsigned pv = ((const unsigned*)(T + ((size_t)s * Gr + g) * NOUT))[sub];
        float* p = accum + (size_t)d * NOUT + sub * 2;
        unsafeAtomicAdd(p, lo16(pv) * nm);
        unsafeAtomicAdd(p + 1, hi16(pv) * nm);
    }
}

__global__ void write_out(const float* __restrict__ acc, void* __restrict__ dout, int n,
                          const int* __restrict__ flagp) {
    int flag = *flagp;
    int i = blockIdx.x * 256 + threadIdx.x;
    if (i >= n) return;
    float v = acc[i];
    if (flag) ((unsigned short*)dout)[i] = f2bf(v);
    else      ((float*)dout)[i] = v;
}

extern "C" void kernel_launch(void* const* d_in, const int* in_sizes, int n_in,
                              void* d_out, int out_size, void* d_ws, size_t ws_size,
                              hipStream_t stream) {
    const void* feat = d_in[0];
    const void* norm = d_in[1];
    const void* W1 = d_in[2];
    const void* W2 = d_in[3];
    const int* src = (const int*)d_in[4];
    const int* dst = (const int*)d_in[5];
    const int* et  = (const int*)d_in[6];

    const int nnodes = in_sizes[0] / 128;
    const int nedges = in_sizes[1];

    char* ws = (char*)d_ws;
    size_t off = 0;
    auto alloc = [&](size_t bytes) { size_t o = off; off += (bytes + 255) & ~255ULL; return o; };
    size_t off_flag = alloc(4);
    size_t off_w1t  = alloc((size_t)R_NUM * 128 * 128 * 2);
    size_t off_w2t  = alloc((size_t)R_NUM * 64 * 128 * 2);

    int* flagp = (int*)(ws + off_flag);
    unsigned short* w1t = (unsigned short*)(ws + off_w1t);
    unsigned short* w2t = (unsigned short*)(ws + off_w2t);

    // fast-path layout
    size_t f_off = off;
    auto falloc = [&](size_t bytes) { size_t o = f_off; f_off += (bytes + 255) & ~255ULL; return o; };
    size_t off_offs = falloc((size_t)(nnodes + 1) * 4);
    size_t off_curs = falloc((size_t)nnodes * 4);
    size_t off_cnt  = falloc((size_t)nnodes * 4);
    size_t off_bsum = falloc(1024 * 4);
    size_t off_boff = falloc(1024 * 4);
    size_t off_pay  = falloc((size_t)nedges * 8);
    size_t off_hbf  = falloc((size_t)nnodes * 128 * 2);
    size_t off_t    = falloc((size_t)nnodes * R_NUM * 128 * 2);
    const int nb = (nnodes + 1023) / 1024;
    bool fast = (f_off <= ws_size) && (nb <= 1024);

    const int gx = (nnodes + 63) / 64;
    const int ntr = R_NUM * 128 * 128 + R_NUM * 128 * 64;

    detect_dtype<<<1, 256, 0, stream>>>((const unsigned short*)feat, flagp);
    transpose_both<<<(ntr + 255) / 256, 256, 0, stream>>>(W1, W2, w1t, w2t, flagp);

    if (fast) {
        int* offs = (int*)(ws + off_offs);
        int* curs = (int*)(ws + off_curs);
        int* cnt  = (int*)(ws + off_cnt);
        int* bsum = (int*)(ws + off_bsum);
        int* boff = (int*)(ws + off_boff);
        uint2* pay = (uint2*)(ws + off_pay);
        unsigned short* hbf = (unsigned short*)(ws + off_hbf);
        unsigned short* t = (unsigned short*)(ws + off_t);

        hipMemsetAsync(cnt, 0, (size_t)nnodes * 4, stream);
        hist_dst<<<(nedges + 255) / 256, 256, 0, stream>>>(dst, cnt, nedges);
        scan_phase1<<<nb, 256, 0, stream>>>(cnt, bsum, nnodes);
        scan_phase2<<<1, 1024, 0, stream>>>(bsum, boff, nb);
        scan_phase3<<<nb, 256, 0, stream>>>(cnt, boff, offs, curs, nnodes);
        fill_payload<<<(nedges + 255) / 256, 256, 0, stream>>>(src, dst, et, norm, flagp,
                                                               curs, pay, nedges);

        gemm_all<128, 0><<<gx, 256, 0, stream>>>(feat, w1t, t, nnodes, flagp);
        gather_seg<128, 0><<<(nnodes + 3) / 4, 256, 0, stream>>>(t, offs, pay, hbf, nnodes, flagp);
        gemm_all<64, 2><<<gx, 256, 0, stream>>>(hbf, w2t, t, nnodes, flagp);
        gather_seg<64, 1><<<(nnodes + 7) / 8, 256, 0, stream>>>(t, offs, pay, d_out, nnodes, flagp);
        return;
    }

    // fallback: chunked atomic path
    size_t off_hpre = alloc((size_t)nnodes * 128 * 4);
    size_t off_oacc = alloc((size_t)nnodes * 64 * 4);
    size_t t_cap = (ws_size > off) ? (ws_size - off) : 0;
    auto pick_gr = [&](int ncol) {
        int gr = 0;
        for (int g = 16; g >= 1; g >>= 1)
            if ((size_t)nnodes * g * ncol * 2 <= t_cap) { gr = g; break; }
        return gr;
    };
    int Gr1 = pick_gr(128);
    int Gr2 = pick_gr(64);
    if (Gr1 < 1 || Gr2 < 1) {
        hipMemsetAsync(d_out, 0x42, (size_t)out_size * 2, stream);
        return;
    }
    float* hpre = (float*)(ws + off_hpre);
    float* oacc = (float*)(ws + off_oacc);
    unsigned short* t = (unsigned short*)(ws + off);

    hipMemsetAsync(hpre, 0, (size_t)nnodes * 128 * 4, stream);
    hipMemsetAsync(oacc, 0, (size_t)nnodes * 64 * 4, stream);
    for (int rb = 0; rb < R_NUM; rb += Gr1) {
        gemm_rel<128, 0><<<dim3(gx, Gr1), 256, 0, stream>>>(feat, w1t, t, nnodes, rb, flagp);
        scatter_k<128><<<4096, 256, 0, stream>>>(t, Gr1, rb, norm, flagp, src, dst, et, hpre, nedges);
    }
    for (int rb = 0; rb < R_NUM; rb += Gr2) {
        gemm_rel<64, 1><<<dim3(gx, Gr2), 256, 0, stream>>>(hpre, w2t, t, nnodes, rb, flagp);
        scatter_k<64><<<4096, 256, 0, stream>>>(t, Gr2, rb, norm, flagp, src, dst, et, oacc, nedges);
    }
    int nout = nnodes * 64;
    write_out<<<(nout + 255) / 256, 256, 0, stream>>>(oacc, d_out, nout, flagp);
}

// Round 6
// 403.549 us; speedup vs baseline: 3.2481x; 1.0127x over previous
//
#include <hip/hip_runtime.h>

// RGCN on MI355X — round 6: coalesced GEMM C-store via LDS staging
// (round-5 gemm was scattered-2B-store bound: 2 TB/s, MfmaUtil 9%).
// Fast path:
//   t1 = feat @ W1[all 16 r]  (block = 64-node tile, rel-loop, A-frags in regs,
//                              acc -> LDS stage -> dwordx4 coalesced store)
//   CSR(dst): hist -> 3-phase parallel scan -> fill payload
//   gather1 (wave/dst)  -> h = relu(.) bf16
//   t2 = h @ W2[all r]  -> gather2 (half-wave/dst) -> d_out
// Fallback (small ws): chunked atomic path.

#define R_NUM 16

typedef __attribute__((ext_vector_type(8))) short bf16x8;
typedef __attribute__((ext_vector_type(4))) float f32x4;

__device__ __forceinline__ float bf2f(unsigned short u) {
    unsigned int x = ((unsigned int)u) << 16;
    return __builtin_bit_cast(float, x);
}
__device__ __forceinline__ unsigned short f2bf(float f) {
    unsigned int x = __builtin_bit_cast(unsigned int, f);
    x += 0x7FFFu + ((x >> 16) & 1u);  // RNE
    return (unsigned short)(x >> 16);
}
__device__ __forceinline__ unsigned pack2(float a, float b) {
    return (unsigned)f2bf(a) | ((unsigned)f2bf(b) << 16);
}
__device__ __forceinline__ float lo16(unsigned v) { return bf2f((unsigned short)(v & 0xFFFF)); }
__device__ __forceinline__ float hi16(unsigned v) { return bf2f((unsigned short)(v >> 16)); }

// ---------------- dtype sniffer (fp32 vs bf16 harness inputs) ----------------
__global__ void detect_dtype(const unsigned short* __restrict__ raw, int* flag) {
    __shared__ int tot;
    if (threadIdx.x == 0) tot = 0;
    __syncthreads();
    int c = 0;
    for (int i = threadIdx.x; i < 4096; i += 256) {
        unsigned short u = raw[2 * i];
        int e = (u >> 7) & 0xFF;
        if (e >= 113 && e <= 134) c++;
    }
    atomicAdd(&tot, c);
    __syncthreads();
    if (threadIdx.x == 0) *flag = (tot > 2048) ? 1 : 0;  // 1 => bf16 inputs
}

// Both weight transposes in one launch: W[r][k][o] -> Wt[r][o][k] bf16.
__global__ void transpose_both(const void* __restrict__ W1, const void* __restrict__ W2,
                               unsigned short* __restrict__ w1t, unsigned short* __restrict__ w2t,
                               const int* __restrict__ flagp) {
    const int flag = *flagp;
    const int n1 = R_NUM * 128 * 128;
    const int n2 = R_NUM * 128 * 64;
    int idx = blockIdx.x * 256 + threadIdx.x;
    if (idx < n1) {
        int k = idx % 128, o = (idx / 128) % 128, r = idx / (128 * 128);
        int iin = (r * 128 + k) * 128 + o;
        float v = flag ? bf2f(((const unsigned short*)W1)[iin]) : ((const float*)W1)[iin];
        w1t[idx] = f2bf(v);
    } else if (idx < n1 + n2) {
        int j = idx - n1;
        int k = j % 128, o = (j / 128) % 64, r = j / (128 * 64);
        int iin = (r * 128 + k) * 64 + o;
        float v = flag ? bf2f(((const unsigned short*)W2)[iin]) : ((const float*)W2)[iin];
        w2t[j] = f2bf(v);
    }
}

// ---------------- GEMM over all relations ----------------
// A-tile staged once -> A-frags hoisted to regs; lA then reused as the
// C-store staging buffer so every t-store is a coalesced dwordx4.
template <int NOUT, int AMODE>
__global__ __launch_bounds__(256, 3) void gemm_all(const void* __restrict__ Asrc,
                                                   const unsigned short* __restrict__ Wt,
                                                   unsigned short* __restrict__ T, int nnodes,
                                                   const int* __restrict__ flagp) {
    constexpr int LDA = 136;
    constexpr int NTC = NOUT / 64;
    __shared__ unsigned short lA[64 * LDA];   // A-tile, then C-store staging
    __shared__ unsigned short lB[NOUT * LDA];
    const int tid = threadIdx.x;
    const int node0 = blockIdx.x * 64;
    const int flag = (AMODE == 0) ? *flagp : 1;

    for (int i = tid; i < 64 * 16; i += 256) {
        int row = i >> 4, seg = i & 15;
        int node = node0 + row;
        uint4 v = make_uint4(0u, 0u, 0u, 0u);
        if (node < nnodes) {
            if (AMODE == 2 || flag) {
                v = *(const uint4*)((const unsigned short*)Asrc + (size_t)node * 128 + seg * 8);
            } else {
                const float* p = (const float*)Asrc + (size_t)node * 128 + seg * 8;
                float4 f0 = ((const float4*)p)[0];
                float4 f1 = ((const float4*)p)[1];
                v.x = pack2(f0.x, f0.y);
                v.y = pack2(f0.z, f0.w);
                v.z = pack2(f1.x, f1.y);
                v.w = pack2(f1.z, f1.w);
            }
        }
        *(uint4*)(lA + row * LDA + seg * 8) = v;
    }

    auto stageB = [&](int rel) {
        for (int i = tid; i < NOUT * 16; i += 256) {
            int o = i >> 4, seg = i & 15;
            *(uint4*)(lB + o * LDA + seg * 8) =
                *(const uint4*)(Wt + ((size_t)rel * NOUT + o) * 128 + seg * 8);
        }
    };
    stageB(0);
    __syncthreads();

    const int w = tid >> 6, lane = tid & 63;
    const int quad = lane >> 4, mr = lane & 15;

    bf16x8 afr[16];
#pragma unroll
    for (int mt = 0; mt < 4; mt++)
#pragma unroll
        for (int kk = 0; kk < 4; kk++)
            afr[mt * 4 + kk] = *(const bf16x8*)(lA + (mt * 16 + mr) * LDA + kk * 32 + quad * 8);

    constexpr int SPT = NOUT / 32;        // dwordx4 store iterations per thread
    constexpr int SEGS = NOUT / 8;        // 16B segments per node row

    for (int rel = 0; rel < R_NUM; rel++) {
        f32x4 acc[4][NTC];
#pragma unroll
        for (int mt = 0; mt < 4; mt++)
#pragma unroll
            for (int c = 0; c < NTC; c++) acc[mt][c] = 0.f;

#pragma unroll
        for (int kk = 0; kk < 4; kk++) {
#pragma unroll
            for (int c = 0; c < NTC; c++) {
                bf16x8 b = *(const bf16x8*)(lB + (c * 64 + w * 16 + mr) * LDA + kk * 32 + quad * 8);
#pragma unroll
                for (int mt = 0; mt < 4; mt++)
                    acc[mt][c] = __builtin_amdgcn_mfma_f32_16x16x32_bf16(afr[mt * 4 + kk], b,
                                                                         acc[mt][c], 0, 0, 0);
            }
        }
        __syncthreads();  // all waves done reading lB (and lA staging free)

        if (rel + 1 < R_NUM) stageB(rel + 1);
        // acc -> LDS staging (row-major, stride LDA)
#pragma unroll
        for (int mt = 0; mt < 4; mt++)
#pragma unroll
            for (int c = 0; c < NTC; c++)
#pragma unroll
                for (int reg = 0; reg < 4; reg++)
                    lA[(mt * 16 + quad * 4 + reg) * LDA + c * 64 + w * 16 + mr] =
                        f2bf(acc[mt][c][reg]);
        __syncthreads();  // lB(rel+1) ready, staging ready

        // coalesced t-store: SPT x 4KB-contiguous dwordx4 per thread
#pragma unroll
        for (int it = 0; it < SPT; it++) {
            int i = it * 256 + tid;
            int row = i / SEGS, seg = i % SEGS;
            int node = node0 + row;
            if (node < nnodes)
                *(uint4*)(T + ((size_t)node * R_NUM + rel) * NOUT + seg * 8) =
                    *(const uint4*)(lA + row * LDA + seg * 8);
        }
    }
}

// ---------------- CSR build ----------------
__global__ void hist_dst(const int* __restrict__ dst, int* __restrict__ counts, int nedges) {
    int e = blockIdx.x * 256 + threadIdx.x;
    if (e < nedges) atomicAdd(&counts[dst[e]], 1);
}

__global__ __launch_bounds__(256) void scan_phase1(const int* __restrict__ counts,
                                                   int* __restrict__ blocksums, int n) {
    __shared__ int red[256];
    int base = blockIdx.x * 1024 + threadIdx.x * 4;
    int s = 0;
#pragma unroll
    for (int j = 0; j < 4; j++) {
        int idx = base + j;
        if (idx < n) s += counts[idx];
    }
    red[threadIdx.x] = s;
    __syncthreads();
    for (int d = 128; d > 0; d >>= 1) {
        if (threadIdx.x < d) red[threadIdx.x] += red[threadIdx.x + d];
        __syncthreads();
    }
    if (threadIdx.x == 0) blocksums[blockIdx.x] = red[0];
}

__global__ __launch_bounds__(1024) void scan_phase2(const int* __restrict__ blocksums,
                                                    int* __restrict__ blockoff, int nb) {
    __shared__ int arr[1024];
    int t = threadIdx.x;
    arr[t] = (t < nb) ? blocksums[t] : 0;
    __syncthreads();
    for (int d = 1; d < 1024; d <<= 1) {
        int v = (t >= d) ? arr[t - d] : 0;
        __syncthreads();
        arr[t] += v;
        __syncthreads();
    }
    if (t < nb) blockoff[t] = (t == 0) ? 0 : arr[t - 1];
}

__global__ __launch_bounds__(256) void scan_phase3(const int* __restrict__ counts,
                                                   const int* __restrict__ blockoff,
                                                   int* __restrict__ offsets,
                                                   int* __restrict__ cursor, int n) {
    __shared__ int tsum[256];
    int base = blockIdx.x * 1024 + threadIdx.x * 4;
    int c[4];
    int s = 0;
#pragma unroll
    for (int j = 0; j < 4; j++) {
        int idx = base + j;
        c[j] = (idx < n) ? counts[idx] : 0;
        s += c[j];
    }
    tsum[threadIdx.x] = s;
    __syncthreads();
    for (int d = 1; d < 256; d <<= 1) {
        int v = (threadIdx.x >= d) ? tsum[threadIdx.x - d] : 0;
        __syncthreads();
        tsum[threadIdx.x] += v;
        __syncthreads();
    }
    int run = blockoff[blockIdx.x] + ((threadIdx.x == 0) ? 0 : tsum[threadIdx.x - 1]);
#pragma unroll
    for (int j = 0; j < 4; j++) {
        int idx = base + j;
        if (idx < n) {
            offsets[idx] = run;
            cursor[idx] = run;
            if (idx == n - 1) offsets[n] = run + c[j];
            run += c[j];
        }
    }
}

__global__ void fill_payload(const int* __restrict__ src, const int* __restrict__ dst,
                             const int* __restrict__ et, const void* __restrict__ nrm,
                             const int* __restrict__ flagp, int* __restrict__ cursor,
                             uint2* __restrict__ payload, int nedges) {
    int e = blockIdx.x * 256 + threadIdx.x;
    if (e >= nedges) return;
    int flag = *flagp;
    float nm = flag ? bf2f(((const unsigned short*)nrm)[e]) : ((const float*)nrm)[e];
    int pos = atomicAdd(&cursor[dst[e]], 1);
    uint2 pl;
    pl.x = ((unsigned)src[e] << 4) | (unsigned)(et[e] & 15);
    pl.y = __builtin_bit_cast(unsigned, nm);
    payload[pos] = pl;
}

// ---------------- dst-centric gather (atomic-free) ----------------
template <int NOUT, int OUTMODE>
__global__ __launch_bounds__(256) void gather_seg(const unsigned short* __restrict__ T,
                                                  const int* __restrict__ offsets,
                                                  const uint2* __restrict__ payload,
                                                  void* __restrict__ out, int nnodes,
                                                  const int* __restrict__ flagp) {
    constexpr int SUBW = NOUT / 2;
    const int lane = threadIdx.x & 63;
    const int ll = lane & (SUBW - 1);
    const int dpb = 256 / SUBW;
    const int dst = blockIdx.x * dpb + threadIdx.x / SUBW;
    if (dst >= nnodes) return;
    const int base = lane & ~(SUBW - 1);
    const int beg = offsets[dst], end = offsets[dst + 1];
    float ax = 0.f, ay = 0.f;

    for (int i = beg; i < end; i += SUBW) {
        int cnt = min(SUBW, end - i);
        uint2 pl = make_uint2(0u, 0u);
        if (ll < cnt) pl = payload[i + ll];
        int j = 0;
        for (; j + 4 <= cnt; j += 4) {
            unsigned k0 = (unsigned)__shfl((int)pl.x, base + j);
            unsigned k1 = (unsigned)__shfl((int)pl.x, base + j + 1);
            unsigned k2 = (unsigned)__shfl((int)pl.x, base + j + 2);
            unsigned k3 = (unsigned)__shfl((int)pl.x, base + j + 3);
            float n0 = __builtin_bit_cast(float, (unsigned)__shfl((int)pl.y, base + j));
            float n1 = __builtin_bit_cast(float, (unsigned)__shfl((int)pl.y, base + j + 1));
            float n2 = __builtin_bit_cast(float, (unsigned)__shfl((int)pl.y, base + j + 2));
            float n3 = __builtin_bit_cast(float, (unsigned)__shfl((int)pl.y, base + j + 3));
            unsigned v0 = ((const unsigned*)(T + ((size_t)(k0 >> 4) * R_NUM + (k0 & 15)) * NOUT))[ll];
            unsigned v1 = ((const unsigned*)(T + ((size_t)(k1 >> 4) * R_NUM + (k1 & 15)) * NOUT))[ll];
            unsigned v2 = ((const unsigned*)(T + ((size_t)(k2 >> 4) * R_NUM + (k2 & 15)) * NOUT))[ll];
            unsigned v3 = ((const unsigned*)(T + ((size_t)(k3 >> 4) * R_NUM + (k3 & 15)) * NOUT))[ll];
            ax = fmaf(lo16(v0), n0, ax); ay = fmaf(hi16(v0), n0, ay);
            ax = fmaf(lo16(v1), n1, ax); ay = fmaf(hi16(v1), n1, ay);
            ax = fmaf(lo16(v2), n2, ax); ay = fmaf(hi16(v2), n2, ay);
            ax = fmaf(lo16(v3), n3, ax); ay = fmaf(hi16(v3), n3, ay);
        }
        for (; j < cnt; j++) {
            unsigned k = (unsigned)__shfl((int)pl.x, base + j);
            float nm = __builtin_bit_cast(float, (unsigned)__shfl((int)pl.y, base + j));
            unsigned v = ((const unsigned*)(T + ((size_t)(k >> 4) * R_NUM + (k & 15)) * NOUT))[ll];
            ax = fmaf(lo16(v), nm, ax);
            ay = fmaf(hi16(v), nm, ay);
        }
    }
    if (OUTMODE == 0) {
        ((unsigned*)out)[(size_t)dst * SUBW + ll] = pack2(fmaxf(ax, 0.f), fmaxf(ay, 0.f));
    } else {
        if (*flagp) {
            ((unsigned*)out)[(size_t)dst * SUBW + ll] = pack2(ax, ay);
        } else {
            float2 v;
            v.x = ax; v.y = ay;
            ((float2*)out)[(size_t)dst * SUBW + ll] = v;
        }
    }
}

// ---------------- fallback path (chunked + atomics) ----------------
template <int NOUT, int AMODE>
__global__ __launch_bounds__(256) void gemm_rel(const void* __restrict__ Asrc,
                                                const unsigned short* __restrict__ Wt,
                                                unsigned short* __restrict__ T, int nnodes,
                                                int rbase, const int* __restrict__ flagp) {
    constexpr int LDA = 136;
    __shared__ unsigned short lA[64 * LDA];
    __shared__ unsigned short lB[NOUT * LDA];
    const int tid = threadIdx.x;
    const int node0 = blockIdx.x * 64;
    const int rel = rbase + blockIdx.y;
    const int Gr = gridDim.y;
    const int flag = (AMODE == 0) ? *flagp : 1;

    for (int i = tid; i < 64 * 16; i += 256) {
        int row = i >> 4, seg = i & 15;
        int node = node0 + row;
        uint4 v = make_uint4(0u, 0u, 0u, 0u);
        if (node < nnodes) {
            if (AMODE == 1) {
                const float* p = (const float*)Asrc + (size_t)node * 128 + seg * 8;
                float4 f0 = ((const float4*)p)[0];
                float4 f1 = ((const float4*)p)[1];
                v.x = pack2(fmaxf(f0.x, 0.f), fmaxf(f0.y, 0.f));
                v.y = pack2(fmaxf(f0.z, 0.f), fmaxf(f0.w, 0.f));
                v.z = pack2(fmaxf(f1.x, 0.f), fmaxf(f1.y, 0.f));
                v.w = pack2(fmaxf(f1.z, 0.f), fmaxf(f1.w, 0.f));
            } else if (flag) {
                v = *(const uint4*)((const unsigned short*)Asrc + (size_t)node * 128 + seg * 8);
            } else {
                const float* p = (const float*)Asrc + (size_t)node * 128 + seg * 8;
                float4 f0 = ((const float4*)p)[0];
                float4 f1 = ((const float4*)p)[1];
                v.x = pack2(f0.x, f0.y);
                v.y = pack2(f0.z, f0.w);
                v.z = pack2(f1.x, f1.y);
                v.w = pack2(f1.z, f1.w);
            }
        }
        *(uint4*)(lA + row * LDA + seg * 8) = v;
    }
    for (int i = tid; i < NOUT * 16; i += 256) {
        int o = i >> 4, seg = i & 15;
        *(uint4*)(lB + o * LDA + seg * 8) =
            *(const uint4*)(Wt + ((size_t)rel * NOUT + o) * 128 + seg * 8);
    }
    __syncthreads();

    const int w = tid >> 6, lane = tid & 63;
    const int quad = lane >> 4, mr = lane & 15;
    constexpr int NT = NOUT / 16;
    f32x4 acc[NT];
#pragma unroll
    for (int t = 0; t < NT; t++) acc[t] = 0.f;
    const unsigned short* pa = lA + (w * 16 + mr) * LDA + quad * 8;
    const unsigned short* pb = lB + mr * LDA + quad * 8;
#pragma unroll
    for (int kk = 0; kk < 4; kk++) {
        bf16x8 a = *(const bf16x8*)(pa + kk * 32);
#pragma unroll
        for (int nt = 0; nt < NT; nt++) {
            bf16x8 b = *(const bf16x8*)(pb + nt * 16 * LDA + kk * 32);
            acc[nt] = __builtin_amdgcn_mfma_f32_16x16x32_bf16(a, b, acc[nt], 0, 0, 0);
        }
    }
#pragma unroll
    for (int nt = 0; nt < NT; nt++)
#pragma unroll
        for (int reg = 0; reg < 4; reg++) {
            int node = node0 + w * 16 + quad * 4 + reg;
            if (node < nnodes)
                T[((size_t)node * Gr + blockIdx.y) * NOUT + nt * 16 + mr] = f2bf(acc[nt][reg]);
        }
}

template <int NOUT>
__global__ void scatter_k(const unsigned short* __restrict__ T, int Gr, int rbase,
                          const void* __restrict__ nrm, const int* __restrict__ flagp,
                          const int* __restrict__ src, const int* __restrict__ dst,
                          const int* __restrict__ et, float* __restrict__ accum, int nedges) {
    constexpr int LPE = NOUT / 2;
    const int flag = *flagp;
    const int epb = 256 / LPE;
    const int sub = threadIdx.x % LPE;
    const int slot = threadIdx.x / LPE;
    for (int e = blockIdx.x * epb + slot; e < nedges; e += gridDim.x * epb) {
        int g = et[e] - rbase;
        if (g < 0 || g >= Gr) continue;
        int s = src[e], d = dst[e];
        float nm = flag ? bf2f(((const unsigned short*)nrm)[e]) : ((const float*)nrm)[e];
        unsigned pv = ((const unsigned*)(T + ((size_t)s * Gr + g) * NOUT))[sub];
        float* p = accum + (size_t)d * NOUT + sub * 2;
        unsafeAtomicAdd(p, lo16(pv) * nm);
        unsafeAtomicAdd(p + 1, hi16(pv) * nm);
    }
}

__global__ void write_out(const float* __restrict__ acc, void* __restrict__ dout, int n,
                          const int* __restrict__ flagp) {
    int flag = *flagp;
    int i = blockIdx.x * 256 + threadIdx.x;
    if (i >= n) return;
    float v = acc[i];
    if (flag) ((unsigned short*)dout)[i] = f2bf(v);
    else      ((float*)dout)[i] = v;
}

extern "C" void kernel_launch(void* const* d_in, const int* in_sizes, int n_in,
                              void* d_out, int out_size, void* d_ws, size_t ws_size,
                              hipStream_t stream) {
    const void* feat = d_in[0];
    const void* norm = d_in[1];
    const void* W1 = d_in[2];
    const void* W2 = d_in[3];
    const int* src = (const int*)d_in[4];
    const int* dst = (const int*)d_in[5];
    const int* et  = (const int*)d_in[6];

    const int nnodes = in_sizes[0] / 128;
    const int nedges = in_sizes[1];

    char* ws = (char*)d_ws;
    size_t off = 0;
    auto alloc = [&](size_t bytes) { size_t o = off; off += (bytes + 255) & ~255ULL; return o; };
    size_t off_flag = alloc(4);
    size_t off_w1t  = alloc((size_t)R_NUM * 128 * 128 * 2);
    size_t off_w2t  = alloc((size_t)R_NUM * 64 * 128 * 2);

    int* flagp = (int*)(ws + off_flag);
    unsigned short* w1t = (unsigned short*)(ws + off_w1t);
    unsigned short* w2t = (unsigned short*)(ws + off_w2t);

    // fast-path layout
    size_t f_off = off;
    auto falloc = [&](size_t bytes) { size_t o = f_off; f_off += (bytes + 255) & ~255ULL; return o; };
    size_t off_offs = falloc((size_t)(nnodes + 1) * 4);
    size_t off_curs = falloc((size_t)nnodes * 4);
    size_t off_cnt  = falloc((size_t)nnodes * 4);
    size_t off_bsum = falloc(1024 * 4);
    size_t off_boff = falloc(1024 * 4);
    size_t off_pay  = falloc((size_t)nedges * 8);
    size_t off_hbf  = falloc((size_t)nnodes * 128 * 2);
    size_t off_t    = falloc((size_t)nnodes * R_NUM * 128 * 2);
    const int nb = (nnodes + 1023) / 1024;
    bool fast = (f_off <= ws_size) && (nb <= 1024);

    const int gx = (nnodes + 63) / 64;
    const int ntr = R_NUM * 128 * 128 + R_NUM * 128 * 64;

    detect_dtype<<<1, 256, 0, stream>>>((const unsigned short*)feat, flagp);
    transpose_both<<<(ntr + 255) / 256, 256, 0, stream>>>(W1, W2, w1t, w2t, flagp);

    if (fast) {
        int* offs = (int*)(ws + off_offs);
        int* curs = (int*)(ws + off_curs);
        int* cnt  = (int*)(ws + off_cnt);
        int* bsum = (int*)(ws + off_bsum);
        int* boff = (int*)(ws + off_boff);
        uint2* pay = (uint2*)(ws + off_pay);
        unsigned short* hbf = (unsigned short*)(ws + off_hbf);
        unsigned short* t = (unsigned short*)(ws + off_t);

        hipMemsetAsync(cnt, 0, (size_t)nnodes * 4, stream);
        hist_dst<<<(nedges + 255) / 256, 256, 0, stream>>>(dst, cnt, nedges);
        scan_phase1<<<nb, 256, 0, stream>>>(cnt, bsum, nnodes);
        scan_phase2<<<1, 1024, 0, stream>>>(bsum, boff, nb);
        scan_phase3<<<nb, 256, 0, stream>>>(cnt, boff, offs, curs, nnodes);
        fill_payload<<<(nedges + 255) / 256, 256, 0, stream>>>(src, dst, et, norm, flagp,
                                                               curs, pay, nedges);

        gemm_all<128, 0><<<gx, 256, 0, stream>>>(feat, w1t, t, nnodes, flagp);
        gather_seg<128, 0><<<(nnodes + 3) / 4, 256, 0, stream>>>(t, offs, pay, hbf, nnodes, flagp);
        gemm_all<64, 2><<<gx, 256, 0, stream>>>(hbf, w2t, t, nnodes, flagp);
        gather_seg<64, 1><<<(nnodes + 7) / 8, 256, 0, stream>>>(t, offs, pay, d_out, nnodes, flagp);
        return;
    }

    // fallback: chunked atomic path
    size_t off_hpre = alloc((size_t)nnodes * 128 * 4);
    size_t off_oacc = alloc((size_t)nnodes * 64 * 4);
    size_t t_cap = (ws_size > off) ? (ws_size - off) : 0;
    auto pick_gr = [&](int ncol) {
        int gr = 0;
        for (int g = 16; g >= 1; g >>= 1)
            if ((size_t)nnodes * g * ncol * 2 <= t_cap) { gr = g; break; }
        return gr;
    };
    int Gr1 = pick_gr(128);
    int Gr2 = pick_gr(64);
    if (Gr1 < 1 || Gr2 < 1) {
        hipMemsetAsync(d_out, 0x42, (size_t)out_size * 2, stream);
        return;
    }
    float* hpre = (float*)(ws + off_hpre);
    float* oacc = (float*)(ws + off_oacc);
    unsigned short* t = (unsigned short*)(ws + off);

    hipMemsetAsync(hpre, 0, (size_t)nnodes * 128 * 4, stream);
    hipMemsetAsync(oacc, 0, (size_t)nnodes * 64 * 4, stream);
    for (int rb = 0; rb < R_NUM; rb += Gr1) {
        gemm_rel<128, 0><<<dim3(gx, Gr1), 256, 0, stream>>>(feat, w1t, t, nnodes, rb, flagp);
        scatter_k<128><<<4096, 256, 0, stream>>>(t, Gr1, rb, norm, flagp, src, dst, et, hpre, nedges);
    }
    for (int rb = 0; rb < R_NUM; rb += Gr2) {
        gemm_rel<64, 1><<<dim3(gx, Gr2), 256, 0, stream>>>(hpre, w2t, t, nnodes, rb, flagp);
        scatter_k<64><<<4096, 256, 0, stream>>>(t, Gr2, rb, norm, flagp, src, dst, et, oacc, nedges);
    }
    int nout = nnodes * 64;
    write_out<<<(nout + 255) / 256, 256, 0, stream>>>(oacc, d_out, nout, flagp);
}

// Round 7
// 397.997 us; speedup vs baseline: 3.2935x; 1.0139x over previous
//
#include <hip/hip_runtime.h>

// RGCN on MI355X — round 7: rel-major t layout (kills 4KB-stride HBM channel
// aliasing on the GEMM store path) + transposed MFMA so staging is 8x
// ds_write_b64 (2-way, free) instead of 32x ds_write_b16 (4-way).
// Fast path:
//   t1[rel][node][128] = feat @ W1   (block = 64-node tile, rel-loop,
//        A-frags in regs, D^T fragments -> LDS stage -> contiguous 16KB store)
//   CSR(dst): hist -> 3-phase parallel scan -> fill payload
//   gather1 (wave/dst)  -> h = relu(.) bf16
//   t2[rel][node][64] = h @ W2 -> gather2 (half-wave/dst) -> d_out
// Fallback (small ws): chunked atomic path.

#define R_NUM 16

typedef __attribute__((ext_vector_type(8))) short bf16x8;
typedef __attribute__((ext_vector_type(4))) float f32x4;

__device__ __forceinline__ float bf2f(unsigned short u) {
    unsigned int x = ((unsigned int)u) << 16;
    return __builtin_bit_cast(float, x);
}
__device__ __forceinline__ unsigned short f2bf(float f) {
    unsigned int x = __builtin_bit_cast(unsigned int, f);
    x += 0x7FFFu + ((x >> 16) & 1u);  // RNE
    return (unsigned short)(x >> 16);
}
__device__ __forceinline__ unsigned pack2(float a, float b) {
    return (unsigned)f2bf(a) | ((unsigned)f2bf(b) << 16);
}
__device__ __forceinline__ float lo16(unsigned v) { return bf2f((unsigned short)(v & 0xFFFF)); }
__device__ __forceinline__ float hi16(unsigned v) { return bf2f((unsigned short)(v >> 16)); }

// ---------------- dtype sniffer (fp32 vs bf16 harness inputs) ----------------
__global__ void detect_dtype(const unsigned short* __restrict__ raw, int* flag) {
    __shared__ int tot;
    if (threadIdx.x == 0) tot = 0;
    __syncthreads();
    int c = 0;
    for (int i = threadIdx.x; i < 4096; i += 256) {
        unsigned short u = raw[2 * i];
        int e = (u >> 7) & 0xFF;
        if (e >= 113 && e <= 134) c++;
    }
    atomicAdd(&tot, c);
    __syncthreads();
    if (threadIdx.x == 0) *flag = (tot > 2048) ? 1 : 0;  // 1 => bf16 inputs
}

// Both weight transposes in one launch: W[r][k][o] -> Wt[r][o][k] bf16.
__global__ void transpose_both(const void* __restrict__ W1, const void* __restrict__ W2,
                               unsigned short* __restrict__ w1t, unsigned short* __restrict__ w2t,
                               const int* __restrict__ flagp) {
    const int flag = *flagp;
    const int n1 = R_NUM * 128 * 128;
    const int n2 = R_NUM * 128 * 64;
    int idx = blockIdx.x * 256 + threadIdx.x;
    if (idx < n1) {
        int k = idx % 128, o = (idx / 128) % 128, r = idx / (128 * 128);
        int iin = (r * 128 + k) * 128 + o;
        float v = flag ? bf2f(((const unsigned short*)W1)[iin]) : ((const float*)W1)[iin];
        w1t[idx] = f2bf(v);
    } else if (idx < n1 + n2) {
        int j = idx - n1;
        int k = j % 128, o = (j / 128) % 64, r = j / (128 * 64);
        int iin = (r * 128 + k) * 64 + o;
        float v = flag ? bf2f(((const unsigned short*)W2)[iin]) : ((const float*)W2)[iin];
        w2t[j] = f2bf(v);
    }
}

// ---------------- GEMM over all relations ----------------
// Transposed MFMA: acc = mfma(Wfrag, featfrag) = (feat@W)^T fragments, so each
// lane owns 4 consecutive output cols of one node -> ds_write_b64 staging.
// T layout: [rel][node][NOUT] -> per-block per-rel store is one contiguous
// 64*NOUT*2-byte burst (no power-of-2 stride aliasing).
template <int NOUT, int AMODE>
__global__ __launch_bounds__(256, 3) void gemm_all(const void* __restrict__ Asrc,
                                                   const unsigned short* __restrict__ Wt,
                                                   unsigned short* __restrict__ T, int nnodes,
                                                   const int* __restrict__ flagp) {
    constexpr int LDA = 136;
    constexpr int NTC = NOUT / 64;
    __shared__ unsigned short lA[64 * LDA];   // A-tile, then C-store staging
    __shared__ unsigned short lB[NOUT * LDA];
    const int tid = threadIdx.x;
    const int node0 = blockIdx.x * 64;
    const int flag = (AMODE == 0) ? *flagp : 1;

    for (int i = tid; i < 64 * 16; i += 256) {
        int row = i >> 4, seg = i & 15;
        int node = node0 + row;
        uint4 v = make_uint4(0u, 0u, 0u, 0u);
        if (node < nnodes) {
            if (AMODE == 2 || flag) {
                v = *(const uint4*)((const unsigned short*)Asrc + (size_t)node * 128 + seg * 8);
            } else {
                const float* p = (const float*)Asrc + (size_t)node * 128 + seg * 8;
                float4 f0 = ((const float4*)p)[0];
                float4 f1 = ((const float4*)p)[1];
                v.x = pack2(f0.x, f0.y);
                v.y = pack2(f0.z, f0.w);
                v.z = pack2(f1.x, f1.y);
                v.w = pack2(f1.z, f1.w);
            }
        }
        *(uint4*)(lA + row * LDA + seg * 8) = v;
    }

    auto stageB = [&](int rel) {
        for (int i = tid; i < NOUT * 16; i += 256) {
            int o = i >> 4, seg = i & 15;
            *(uint4*)(lB + o * LDA + seg * 8) =
                *(const uint4*)(Wt + ((size_t)rel * NOUT + o) * 128 + seg * 8);
        }
    };
    stageB(0);
    __syncthreads();

    const int w = tid >> 6, lane = tid & 63;
    const int quad = lane >> 4, mr = lane & 15;

    // hoist all A-fragments (whole 64-row tile) into registers
    bf16x8 afr[16];
#pragma unroll
    for (int mt = 0; mt < 4; mt++)
#pragma unroll
        for (int kk = 0; kk < 4; kk++)
            afr[mt * 4 + kk] = *(const bf16x8*)(lA + (mt * 16 + mr) * LDA + kk * 32 + quad * 8);

    constexpr int SEGS = NOUT / 8;            // 16B segments per node row
    constexpr int SPT = 64 * SEGS / 256;      // dwordx4 stores per thread

    for (int rel = 0; rel < R_NUM; rel++) {
        f32x4 acc[4][NTC];  // acc[mt][c] = t^T fragment: node=mt*16+mr, cols quad*4+reg
#pragma unroll
        for (int mt = 0; mt < 4; mt++)
#pragma unroll
            for (int c = 0; c < NTC; c++) acc[mt][c] = 0.f;

#pragma unroll
        for (int kk = 0; kk < 4; kk++) {
#pragma unroll
            for (int c = 0; c < NTC; c++) {
                bf16x8 b = *(const bf16x8*)(lB + (c * 64 + w * 16 + mr) * LDA + kk * 32 + quad * 8);
#pragma unroll
                for (int mt = 0; mt < 4; mt++)
                    acc[mt][c] = __builtin_amdgcn_mfma_f32_16x16x32_bf16(b, afr[mt * 4 + kk],
                                                                         acc[mt][c], 0, 0, 0);
            }
        }
        __syncthreads();  // compute done: lB free to restage, lA free to stage C

        if (rel + 1 < R_NUM) stageB(rel + 1);
        // acc -> LDS staging: one b64 per (mt,c); 2-way bank alias only
#pragma unroll
        for (int mt = 0; mt < 4; mt++)
#pragma unroll
            for (int c = 0; c < NTC; c++) {
                uint2 pv;
                pv.x = pack2(acc[mt][c][0], acc[mt][c][1]);
                pv.y = pack2(acc[mt][c][2], acc[mt][c][3]);
                *(uint2*)(lA + (mt * 16 + mr) * LDA + c * 64 + w * 16 + quad * 4) = pv;
            }
        __syncthreads();  // staging + lB(rel+1) ready

        // contiguous store: block writes 64*NOUT*2 B sequential at T[rel][node0]
#pragma unroll
        for (int it = 0; it < SPT; it++) {
            int i = it * 256 + tid;
            int row = i / SEGS, seg = i % SEGS;
            int node = node0 + row;
            if (node < nnodes)
                *(uint4*)(T + ((size_t)rel * nnodes + node) * NOUT + seg * 8) =
                    *(const uint4*)(lA + row * LDA + seg * 8);
        }
    }
}

// ---------------- CSR build ----------------
__global__ void hist_dst(const int* __restrict__ dst, int* __restrict__ counts, int nedges) {
    int e = blockIdx.x * 256 + threadIdx.x;
    if (e < nedges) atomicAdd(&counts[dst[e]], 1);
}

__global__ __launch_bounds__(256) void scan_phase1(const int* __restrict__ counts,
                                                   int* __restrict__ blocksums, int n) {
    __shared__ int red[256];
    int base = blockIdx.x * 1024 + threadIdx.x * 4;
    int s = 0;
#pragma unroll
    for (int j = 0; j < 4; j++) {
        int idx = base + j;
        if (idx < n) s += counts[idx];
    }
    red[threadIdx.x] = s;
    __syncthreads();
    for (int d = 128; d > 0; d >>= 1) {
        if (threadIdx.x < d) red[threadIdx.x] += red[threadIdx.x + d];
        __syncthreads();
    }
    if (threadIdx.x == 0) blocksums[blockIdx.x] = red[0];
}

__global__ __launch_bounds__(1024) void scan_phase2(const int* __restrict__ blocksums,
                                                    int* __restrict__ blockoff, int nb) {
    __shared__ int arr[1024];
    int t = threadIdx.x;
    arr[t] = (t < nb) ? blocksums[t] : 0;
    __syncthreads();
    for (int d = 1; d < 1024; d <<= 1) {
        int v = (t >= d) ? arr[t - d] : 0;
        __syncthreads();
        arr[t] += v;
        __syncthreads();
    }
    if (t < nb) blockoff[t] = (t == 0) ? 0 : arr[t - 1];
}

__global__ __launch_bounds__(256) void scan_phase3(const int* __restrict__ counts,
                                                   const int* __restrict__ blockoff,
                                                   int* __restrict__ offsets,
                                                   int* __restrict__ cursor, int n) {
    __shared__ int tsum[256];
    int base = blockIdx.x * 1024 + threadIdx.x * 4;
    int c[4];
    int s = 0;
#pragma unroll
    for (int j = 0; j < 4; j++) {
        int idx = base + j;
        c[j] = (idx < n) ? counts[idx] : 0;
        s += c[j];
    }
    tsum[threadIdx.x] = s;
    __syncthreads();
    for (int d = 1; d < 256; d <<= 1) {
        int v = (threadIdx.x >= d) ? tsum[threadIdx.x - d] : 0;
        __syncthreads();
        tsum[threadIdx.x] += v;
        __syncthreads();
    }
    int run = blockoff[blockIdx.x] + ((threadIdx.x == 0) ? 0 : tsum[threadIdx.x - 1]);
#pragma unroll
    for (int j = 0; j < 4; j++) {
        int idx = base + j;
        if (idx < n) {
            offsets[idx] = run;
            cursor[idx] = run;
            if (idx == n - 1) offsets[n] = run + c[j];
            run += c[j];
        }
    }
}

__global__ void fill_payload(const int* __restrict__ src, const int* __restrict__ dst,
                             const int* __restrict__ et, const void* __restrict__ nrm,
                             const int* __restrict__ flagp, int* __restrict__ cursor,
                             uint2* __restrict__ payload, int nedges) {
    int e = blockIdx.x * 256 + threadIdx.x;
    if (e >= nedges) return;
    int flag = *flagp;
    float nm = flag ? bf2f(((const unsigned short*)nrm)[e]) : ((const float*)nrm)[e];
    int pos = atomicAdd(&cursor[dst[e]], 1);
    uint2 pl;
    pl.x = ((unsigned)src[e] << 4) | (unsigned)(et[e] & 15);
    pl.y = __builtin_bit_cast(unsigned, nm);
    payload[pos] = pl;
}

// ---------------- dst-centric gather (atomic-free) ----------------
// T is rel-major: row = T[(et*nnodes + src)*NOUT].
template <int NOUT, int OUTMODE>
__global__ __launch_bounds__(256) void gather_seg(const unsigned short* __restrict__ T,
                                                  const int* __restrict__ offsets,
                                                  const uint2* __restrict__ payload,
                                                  void* __restrict__ out, int nnodes,
                                                  const int* __restrict__ flagp) {
    constexpr int SUBW = NOUT / 2;
    const int lane = threadIdx.x & 63;
    const int ll = lane & (SUBW - 1);
    const int dpb = 256 / SUBW;
    const int dst = blockIdx.x * dpb + threadIdx.x / SUBW;
    if (dst >= nnodes) return;
    const int base = lane & ~(SUBW - 1);
    const int beg = offsets[dst], end = offsets[dst + 1];
    float ax = 0.f, ay = 0.f;

    auto rowp = [&](unsigned key) {
        return (const unsigned*)(T + ((size_t)(key & 15) * nnodes + (key >> 4)) * NOUT);
    };

    for (int i = beg; i < end; i += SUBW) {
        int cnt = min(SUBW, end - i);
        uint2 pl = make_uint2(0u, 0u);
        if (ll < cnt) pl = payload[i + ll];
        int j = 0;
        for (; j + 4 <= cnt; j += 4) {
            unsigned k0 = (unsigned)__shfl((int)pl.x, base + j);
            unsigned k1 = (unsigned)__shfl((int)pl.x, base + j + 1);
            unsigned k2 = (unsigned)__shfl((int)pl.x, base + j + 2);
            unsigned k3 = (unsigned)__shfl((int)pl.x, base + j + 3);
            float n0 = __builtin_bit_cast(float, (unsigned)__shfl((int)pl.y, base + j));
            float n1 = __builtin_bit_cast(float, (unsigned)__shfl((int)pl.y, base + j + 1));
            float n2 = __builtin_bit_cast(float, (unsigned)__shfl((int)pl.y, base + j + 2));
            float n3 = __builtin_bit_cast(float, (unsigned)__shfl((int)pl.y, base + j + 3));
            unsigned v0 = rowp(k0)[ll];
            unsigned v1 = rowp(k1)[ll];
            unsigned v2 = rowp(k2)[ll];
            unsigned v3 = rowp(k3)[ll];
            ax = fmaf(lo16(v0), n0, ax); ay = fmaf(hi16(v0), n0, ay);
            ax = fmaf(lo16(v1), n1, ax); ay = fmaf(hi16(v1), n1, ay);
            ax = fmaf(lo16(v2), n2, ax); ay = fmaf(hi16(v2), n2, ay);
            ax = fmaf(lo16(v3), n3, ax); ay = fmaf(hi16(v3), n3, ay);
        }
        for (; j < cnt; j++) {
            unsigned k = (unsigned)__shfl((int)pl.x, base + j);
            float nm = __builtin_bit_cast(float, (unsigned)__shfl((int)pl.y, base + j));
            unsigned v = rowp(k)[ll];
            ax = fmaf(lo16(v), nm, ax);
            ay = fmaf(hi16(v), nm, ay);
        }
    }
    if (OUTMODE == 0) {
        ((unsigned*)out)[(size_t)dst * SUBW + ll] = pack2(fmaxf(ax, 0.f), fmaxf(ay, 0.f));
    } else {
        if (*flagp) {
            ((unsigned*)out)[(size_t)dst * SUBW + ll] = pack2(ax, ay);
        } else {
            float2 v;
            v.x = ax; v.y = ay;
            ((float2*)out)[(size_t)dst * SUBW + ll] = v;
        }
    }
}

// ---------------- fallback path (chunked + atomics, node-major t) ----------------
template <int NOUT, int AMODE>
__global__ __launch_bounds__(256) void gemm_rel(const void* __restrict__ Asrc,
                                                const unsigned short* __restrict__ Wt,
                                                unsigned short* __restrict__ T, int nnodes,
                                                int rbase, const int* __restrict__ flagp) {
    constexpr int LDA = 136;
    __shared__ unsigned short lA[64 * LDA];
    __shared__ unsigned short lB[NOUT * LDA];
    const int tid = threadIdx.x;
    const int node0 = blockIdx.x * 64;
    const int rel = rbase + blockIdx.y;
    const int Gr = gridDim.y;
    const int flag = (AMODE == 0) ? *flagp : 1;

    for (int i = tid; i < 64 * 16; i += 256) {
        int row = i >> 4, seg = i & 15;
        int node = node0 + row;
        uint4 v = make_uint4(0u, 0u, 0u, 0u);
        if (node < nnodes) {
            if (AMODE == 1) {
                const float* p = (const float*)Asrc + (size_t)node * 128 + seg * 8;
                float4 f0 = ((const float4*)p)[0];
                float4 f1 = ((const float4*)p)[1];
                v.x = pack2(fmaxf(f0.x, 0.f), fmaxf(f0.y, 0.f));
                v.y = pack2(fmaxf(f0.z, 0.f), fmaxf(f0.w, 0.f));
                v.z = pack2(fmaxf(f1.x, 0.f), fmaxf(f1.y, 0.f));
                v.w = pack2(fmaxf(f1.z, 0.f), fmaxf(f1.w, 0.f));
            } else if (flag) {
                v = *(const uint4*)((const unsigned short*)Asrc + (size_t)node * 128 + seg * 8);
            } else {
                const float* p = (const float*)Asrc + (size_t)node * 128 + seg * 8;
                float4 f0 = ((const float4*)p)[0];
                float4 f1 = ((const float4*)p)[1];
                v.x = pack2(f0.x, f0.y);
                v.y = pack2(f0.z, f0.w);
                v.z = pack2(f1.x, f1.y);
                v.w = pack2(f1.z, f1.w);
            }
        }
        *(uint4*)(lA + row * LDA + seg * 8) = v;
    }
    for (int i = tid; i < NOUT * 16; i += 256) {
        int o = i >> 4, seg = i & 15;
        *(uint4*)(lB + o * LDA + seg * 8) =
            *(const uint4*)(Wt + ((size_t)rel * NOUT + o) * 128 + seg * 8);
    }
    __syncthreads();

    const int w = tid >> 6, lane = tid & 63;
    const int quad = lane >> 4, mr = lane & 15;
    constexpr int NT = NOUT / 16;
    f32x4 acc[NT];
#pragma unroll
    for (int t = 0; t < NT; t++) acc[t] = 0.f;
    const unsigned short* pa = lA + (w * 16 + mr) * LDA + quad * 8;
    const unsigned short* pb = lB + mr * LDA + quad * 8;
#pragma unroll
    for (int kk = 0; kk < 4; kk++) {
        bf16x8 a = *(const bf16x8*)(pa + kk * 32);
#pragma unroll
        for (int nt = 0; nt < NT; nt++) {
            bf16x8 b = *(const bf16x8*)(pb + nt * 16 * LDA + kk * 32);
            acc[nt] = __builtin_amdgcn_mfma_f32_16x16x32_bf16(a, b, acc[nt], 0, 0, 0);
        }
    }
#pragma unroll
    for (int nt = 0; nt < NT; nt++)
#pragma unroll
        for (int reg = 0; reg < 4; reg++) {
            int node = node0 + w * 16 + quad * 4 + reg;
            if (node < nnodes)
                T[((size_t)node * Gr + blockIdx.y) * NOUT + nt * 16 + mr] = f2bf(acc[nt][reg]);
        }
}

template <int NOUT>
__global__ void scatter_k(const unsigned short* __restrict__ T, int Gr, int rbase,
                          const void* __restrict__ nrm, const int* __restrict__ flagp,
                          const int* __restrict__ src, const int* __restrict__ dst,
                          const int* __restrict__ et, float* __restrict__ accum, int nedges) {
    constexpr int LPE = NOUT / 2;
    const int flag = *flagp;
    const int epb = 256 / LPE;
    const int sub = threadIdx.x % LPE;
    const int slot = threadIdx.x / LPE;
    for (int e = blockIdx.x * epb + slot; e < nedges; e += gridDim.x * epb) {
        int g = et[e] - rbase;
        if (g < 0 || g >= Gr) continue;
        int s = src[e], d = dst[e];
        float nm = flag ? bf2f(((const unsigned short*)nrm)[e]) : ((const float*)nrm)[e];
        unsigned pv = ((const unsigned*)(T + ((size_t)s * Gr + g) * NOUT))[sub];
        float* p = accum + (size_t)d * NOUT + sub * 2;
        unsafeAtomicAdd(p, lo16(pv) * nm);
        unsafeAtomicAdd(p + 1, hi16(pv) * nm);
    }
}

__global__ void write_out(const float* __restrict__ acc, void* __restrict__ dout, int n,
                          const int* __restrict__ flagp) {
    int flag = *flagp;
    int i = blockIdx.x * 256 + threadIdx.x;
    if (i >= n) return;
    float v = acc[i];
    if (flag) ((unsigned short*)dout)[i] = f2bf(v);
    else      ((float*)dout)[i] = v;
}

extern "C" void kernel_launch(void* const* d_in, const int* in_sizes, int n_in,
                              void* d_out, int out_size, void* d_ws, size_t ws_size,
                              hipStream_t stream) {
    const void* feat = d_in[0];
    const void* norm = d_in[1];
    const void* W1 = d_in[2];
    const void* W2 = d_in[3];
    const int* src = (const int*)d_in[4];
    const int* dst = (const int*)d_in[5];
    const int* et  = (const int*)d_in[6];

    const int nnodes = in_sizes[0] / 128;
    const int nedges = in_sizes[1];

    char* ws = (char*)d_ws;
    size_t off = 0;
    auto alloc = [&](size_t bytes) { size_t o = off; off += (bytes + 255) & ~255ULL; return o; };
    size_t off_flag = alloc(4);
    size_t off_w1t  = alloc((size_t)R_NUM * 128 * 128 * 2);
    size_t off_w2t  = alloc((size_t)R_NUM * 64 * 128 * 2);

    int* flagp = (int*)(ws + off_flag);
    unsigned short* w1t = (unsigned short*)(ws + off_w1t);
    unsigned short* w2t = (unsigned short*)(ws + off_w2t);

    // fast-path layout
    size_t f_off = off;
    auto falloc = [&](size_t bytes) { size_t o = f_off; f_off += (bytes + 255) & ~255ULL; return o; };
    size_t off_offs = falloc((size_t)(nnodes + 1) * 4);
    size_t off_curs = falloc((size_t)nnodes * 4);
    size_t off_cnt  = falloc((size_t)nnodes * 4);
    size_t off_bsum = falloc(1024 * 4);
    size_t off_boff = falloc(1024 * 4);
    size_t off_pay  = falloc((size_t)nedges * 8);
    size_t off_hbf  = falloc((size_t)nnodes * 128 * 2);
    size_t off_t    = falloc((size_t)nnodes * R_NUM * 128 * 2);
    const int nb = (nnodes + 1023) / 1024;
    bool fast = (f_off <= ws_size) && (nb <= 1024);

    const int gx = (nnodes + 63) / 64;
    const int ntr = R_NUM * 128 * 128 + R_NUM * 128 * 64;

    detect_dtype<<<1, 256, 0, stream>>>((const unsigned short*)feat, flagp);
    transpose_both<<<(ntr + 255) / 256, 256, 0, stream>>>(W1, W2, w1t, w2t, flagp);

    if (fast) {
        int* offs = (int*)(ws + off_offs);
        int* curs = (int*)(ws + off_curs);
        int* cnt  = (int*)(ws + off_cnt);
        int* bsum = (int*)(ws + off_bsum);
        int* boff = (int*)(ws + off_boff);
        uint2* pay = (uint2*)(ws + off_pay);
        unsigned short* hbf = (unsigned short*)(ws + off_hbf);
        unsigned short* t = (unsigned short*)(ws + off_t);

        hipMemsetAsync(cnt, 0, (size_t)nnodes * 4, stream);
        hist_dst<<<(nedges + 255) / 256, 256, 0, stream>>>(dst, cnt, nedges);
        scan_phase1<<<nb, 256, 0, stream>>>(cnt, bsum, nnodes);
        scan_phase2<<<1, 1024, 0, stream>>>(bsum, boff, nb);
        scan_phase3<<<nb, 256, 0, stream>>>(cnt, boff, offs, curs, nnodes);
        fill_payload<<<(nedges + 255) / 256, 256, 0, stream>>>(src, dst, et, norm, flagp,
                                                               curs, pay, nedges);

        gemm_all<128, 0><<<gx, 256, 0, stream>>>(feat, w1t, t, nnodes, flagp);
        gather_seg<128, 0><<<(nnodes + 3) / 4, 256, 0, stream>>>(t, offs, pay, hbf, nnodes, flagp);
        gemm_all<64, 2><<<gx, 256, 0, stream>>>(hbf, w2t, t, nnodes, flagp);
        gather_seg<64, 1><<<(nnodes + 7) / 8, 256, 0, stream>>>(t, offs, pay, d_out, nnodes, flagp);
        return;
    }

    // fallback: chunked atomic path
    size_t off_hpre = alloc((size_t)nnodes * 128 * 4);
    size_t off_oacc = alloc((size_t)nnodes * 64 * 4);
    size_t t_cap = (ws_size > off) ? (ws_size - off) : 0;
    auto pick_gr = [&](int ncol) {
        int gr = 0;
        for (int g = 16; g >= 1; g >>= 1)
            if ((size_t)nnodes * g * ncol * 2 <= t_cap) { gr = g; break; }
        return gr;
    };
    int Gr1 = pick_gr(128);
    int Gr2 = pick_gr(64);
    if (Gr1 < 1 || Gr2 < 1) {
        hipMemsetAsync(d_out, 0x42, (size_t)out_size * 2, stream);
        return;
    }
    float* hpre = (float*)(ws + off_hpre);
    float* oacc = (float*)(ws + off_oacc);
    unsigned short* t = (unsigned short*)(ws + off);

    hipMemsetAsync(hpre, 0, (size_t)nnodes * 128 * 4, stream);
    hipMemsetAsync(oacc, 0, (size_t)nnodes * 64 * 4, stream);
    for (int rb = 0; rb < R_NUM; rb += Gr1) {
        gemm_rel<128, 0><<<dim3(gx, Gr1), 256, 0, stream>>>(feat, w1t, t, nnodes, rb, flagp);
        scatter_k<128><<<4096, 256, 0, stream>>>(t, Gr1, rb, norm, flagp, src, dst, et, hpre, nedges);
    }
    for (int rb = 0; rb < R_NUM; rb += Gr2) {
        gemm_rel<64, 1><<<dim3(gx, Gr2), 256, 0, stream>>>(hpre, w2t, t, nnodes, rb, flagp);
        scatter_k<64><<<4096, 256, 0, stream>>>(t, Gr2, rb, norm, flagp, src, dst, et, oacc, nedges);
    }
    int nout = nnodes * 64;
    write_out<<<(nout + 255) / 256, 256, 0, stream>>>(oacc, d_out, nout, flagp);
}